// Round 13
// baseline (352.877 us; speedup 1.0000x reference)
//
#include <hip/hip_runtime.h>

#define BN_EPS 1e-5f

using h8 = __attribute__((ext_vector_type(8))) _Float16;
using h4v = __attribute__((ext_vector_type(4))) _Float16;
using f4v = __attribute__((ext_vector_type(4))) float;

// workspace float offsets (round-7/10/11 proven layout)
#define OFF_COEF 0        // 4 stages x 256 (a @ [0:128), shift @ [128:256))
#define OFF_CVEC 1024     // 128
#define OFF_H1 4096       // 4096x128 (aliased: aggraw; first 16384 = sums4)
#define OFF_P2 528384     // first 16384 floats = sums1 (dead until k_pq1)
#define OFF_Q2 1052672
#define OFF_H3 1576960
#define OFF_P4 2101248    // first 16384 = sums2 (dead until k_pq4)
#define OFF_Q4 2625536    // first 16384 = sums3 (dead until k_pq4)
#define OFF_W2P 3149824   // 16384 fp16 = 8192 floats each
#define OFF_W4P 3158016
#define OFF_WCP 3166208
#define OFF_H4B 3174400   // 258048x128 fp16: h2 then h4 in place
#define WS_BYTES 78757888ull

__device__ __forceinline__ float elu_f(float x) {
    return x > 0.f ? x : __expf(x) - 1.f;
}

// ---------------------------------------------------------------------------
// fp32 tile GEMM helpers (node-level kernels) - proven.
// ---------------------------------------------------------------------------

__device__ __forceinline__ void gemm_acc(float acc[4][8], float a0, float a1, float a2,
                                         float a3, const float4 wa, const float4 wb) {
    const float w[8] = {wa.x, wa.y, wa.z, wa.w, wb.x, wb.y, wb.z, wb.w};
    const float a[4] = {a0, a1, a2, a3};
#pragma unroll
    for (int j = 0; j < 4; ++j)
#pragma unroll
        for (int u = 0; u < 8; ++u)
            acc[j][u] = fmaf(a[j], w[u], acc[j][u]);
}

__device__ __forceinline__ void gemm_globalW(const float* As, int lda,
                                             const float* __restrict__ Wg, int K,
                                             float acc[4][8], int tx, int ty) {
    const float4* Wg4 = (const float4*)Wg;
#pragma unroll 4
    for (int k = 0; k < K; ++k) {
        float a0 = As[ty * lda + k];
        float a1 = As[(ty + 16) * lda + k];
        float a2 = As[(ty + 32) * lda + k];
        float a3 = As[(ty + 48) * lda + k];
        float4 wa = Wg4[k * 32 + tx];
        float4 wb = Wg4[k * 32 + 16 + tx];
        gemm_acc(acc, a0, a1, a2, a3, wa, wb);
    }
}

__device__ __forceinline__ void bias_elu(const float acc[4][8], const float* __restrict__ bias,
                                         float vals[4][8], int tx) {
    int ca = 4 * tx, cb = 64 + 4 * tx;
    float bv[8] = {bias[ca], bias[ca + 1], bias[ca + 2], bias[ca + 3],
                   bias[cb], bias[cb + 1], bias[cb + 2], bias[cb + 3]};
#pragma unroll
    for (int j = 0; j < 4; ++j)
#pragma unroll
        for (int u = 0; u < 8; ++u)
            vals[j][u] = elu_f(acc[j][u] + bv[u]);
}

__device__ __forceinline__ void store_tile(float* __restrict__ out, int row0,
                                           const float vals[4][8], int tx, int ty) {
#pragma unroll
    for (int j = 0; j < 4; ++j) {
        int r = row0 + ty + 16 * j;
        *(float4*)(out + r * 128 + 4 * tx) =
            make_float4(vals[j][0], vals[j][1], vals[j][2], vals[j][3]);
        *(float4*)(out + r * 128 + 64 + 4 * tx) =
            make_float4(vals[j][4], vals[j][5], vals[j][6], vals[j][7]);
    }
}

__device__ __forceinline__ void stats_tail(const float vals[4][8], float* red,
                                           float* __restrict__ st, int tid, int tx, int ty) {
    float ls[8], lq[8];
#pragma unroll
    for (int u = 0; u < 8; ++u) {
        ls[u] = vals[0][u] + vals[1][u] + vals[2][u] + vals[3][u];
        lq[u] = vals[0][u] * vals[0][u] + vals[1][u] * vals[1][u] +
                vals[2][u] * vals[2][u] + vals[3][u] * vals[3][u];
    }
    __syncthreads();
    int ca = 4 * tx, cb = 64 + 4 * tx;
#pragma unroll
    for (int u = 0; u < 4; ++u) {
        red[ty * 128 + ca + u] = ls[u];
        red[2048 + ty * 128 + ca + u] = lq[u];
        red[ty * 128 + cb + u] = ls[u + 4];
        red[2048 + ty * 128 + cb + u] = lq[u + 4];
    }
    __syncthreads();
    if (tid < 128) {
        float s = 0.f, q = 0.f;
#pragma unroll
        for (int t = 0; t < 16; ++t) {
            s += red[t * 128 + tid];
            q += red[2048 + t * 128 + tid];
        }
        atomicAdd(st + tid, s);
        atomicAdd(st + 128 + tid, q);
    }
}

// ---------------------------------------------------------------------------
// MFMA helpers (proven). A-frag LDS layout:
// Afr[((rt*4+kc)*64 + o*16 + m)*8 + j] = act[rt*16+m][kc*32+o*8+j] (fp16).
// Weights prepacked in GLOBAL: Wp[((ct*4+kc)*64+L)*8+j] =
// W[kc*32+(L>>4)*8+j][ct*16+(L&15)]. Wave w computes rows 0..63 x cols
// [32w, 32w+32). gemm2_gw: one weight-frag load feeds BOTH tiles' MFMAs.
// ---------------------------------------------------------------------------

__device__ __forceinline__ void gemm2_gw(const _Float16* A0, const _Float16* A1,
                                         const _Float16* __restrict__ wp,
                                         f4v acc0[4][2], f4v acc1[4][2], int lane, int w) {
#pragma unroll
    for (int kc = 0; kc < 4; ++kc) {
        h8 bf0 = *(const h8*)&wp[(((w * 2 + 0) * 4 + kc) * 64 + lane) * 8];
        h8 bf1 = *(const h8*)&wp[(((w * 2 + 1) * 4 + kc) * 64 + lane) * 8];
        h8 af0[4], af1[4];
#pragma unroll
        for (int rt = 0; rt < 4; ++rt) {
            af0[rt] = *(const h8*)&A0[((rt * 4 + kc) * 64 + lane) * 8];
            af1[rt] = *(const h8*)&A1[((rt * 4 + kc) * 64 + lane) * 8];
        }
#pragma unroll
        for (int rt = 0; rt < 4; ++rt) {
            acc0[rt][0] = __builtin_amdgcn_mfma_f32_16x16x32_f16(af0[rt], bf0, acc0[rt][0], 0, 0, 0);
            acc1[rt][0] = __builtin_amdgcn_mfma_f32_16x16x32_f16(af1[rt], bf0, acc1[rt][0], 0, 0, 0);
        }
#pragma unroll
        for (int rt = 0; rt < 4; ++rt) {
            acc0[rt][1] = __builtin_amdgcn_mfma_f32_16x16x32_f16(af0[rt], bf1, acc0[rt][1], 0, 0, 0);
            acc1[rt][1] = __builtin_amdgcn_mfma_f32_16x16x32_f16(af1[rt], bf1, acc1[rt][1], 0, 0, 0);
        }
    }
}

__device__ __forceinline__ void vals_to_afrag(_Float16* Afr, const float vals[4][2][4],
                                              int lane, int w) {
    int cl = lane & 15, quad = lane >> 4;
#pragma unroll
    for (int ctl = 0; ctl < 2; ++ctl) {
        int col = (w * 2 + ctl) * 16 + cl;
        int kc = col >> 5, o = (col >> 3) & 3, j = col & 7;
#pragma unroll
        for (int rt = 0; rt < 4; ++rt)
#pragma unroll
            for (int i = 0; i < 4; ++i) {
                int m = quad * 4 + i;
                Afr[((rt * 4 + kc) * 64 + o * 16 + m) * 8 + j] = (_Float16)vals[rt][ctl][i];
            }
    }
}

// stage A = elu(P[row] + Q[row] + bias) into A-frag layout (proven)
__device__ __forceinline__ void stage_pair(_Float16* Afr, const float4* __restrict__ Pr,
                                           const float4* __restrict__ Qr,
                                           const float4* __restrict__ B1, int lane, int kc) {
    int rt = lane >> 4, m = lane & 15;
#pragma unroll
    for (int o = 0; o < 4; ++o) {
        int c4 = kc * 8 + o * 2;
        float4 p0 = Pr[c4], q0 = Qr[c4], bb0 = B1[c4];
        float4 p1 = Pr[c4 + 1], q1 = Qr[c4 + 1], bb1 = B1[c4 + 1];
        h8 v;
        v[0] = (_Float16)elu_f(p0.x + q0.x + bb0.x);
        v[1] = (_Float16)elu_f(p0.y + q0.y + bb0.y);
        v[2] = (_Float16)elu_f(p0.z + q0.z + bb0.z);
        v[3] = (_Float16)elu_f(p0.w + q0.w + bb0.w);
        v[4] = (_Float16)elu_f(p1.x + q1.x + bb1.x);
        v[5] = (_Float16)elu_f(p1.y + q1.y + bb1.y);
        v[6] = (_Float16)elu_f(p1.z + q1.z + bb1.z);
        v[7] = (_Float16)elu_f(p1.w + q1.w + bb1.w);
        *(h8*)&Afr[((rt * 4 + kc) * 64 + o * 16 + m) * 8] = v;
    }
}

// ---------------------------------------------------------------------------
// Kernels
// ---------------------------------------------------------------------------

// merged: zero shadow-sum arenas + cvec; pack w2/w4 layer-2 weights to fp16 frag
__global__ void k_prep(float* W, const float* __restrict__ w2src,
                       const float* __restrict__ w4src) {
    int blk = blockIdx.x, tid = threadIdx.x;
    if (blk < 193) {
        int i = blk * 256 + tid;
        if (i < 16384) W[OFF_P2 + i] = 0.f;
        else if (i < 32768) W[OFF_P4 + i - 16384] = 0.f;
        else if (i < 49152) W[OFF_Q4 + i - 32768] = 0.f;
        else if (i < 49280) W[OFF_CVEC + i - 49152] = 0.f;
    } else {
        int second = blk >= 201;
        const float* src = second ? w4src : w2src;
        _Float16* wp = (_Float16*)(W + (second ? OFF_W4P : OFF_W2P));
        int flat = (blk - (second ? 201 : 193)) * 256 + tid;  // 0..2047
        int g = flat >> 6, L = flat & 63;
        int ct = g >> 2, kc = g & 3;
        int nn = ct * 16 + (L & 15), k0 = kc * 32 + (L >> 4) * 8;
        h8 v;
#pragma unroll
        for (int j = 0; j < 8; ++j) v[j] = (_Float16)src[(k0 + j) * 128 + nn];
        *(h8*)&wp[flat * 8] = v;
    }
}

__global__ void k_finalize(const float* __restrict__ sums, float* __restrict__ coef,
                           float invM, const float* __restrict__ g,
                           const float* __restrict__ beta, float* __restrict__ zbuf) {
    int c = threadIdx.x;  // 128
    float s = 0.f, q = 0.f;
#pragma unroll 8
    for (int t = 0; t < 64; ++t) {
        s += sums[t * 256 + c];
        q += sums[t * 256 + 128 + c];
    }
    float mean = s * invM;
    float var = q * invM - mean * mean;
    float a = g[c] * rsqrtf(var + BN_EPS);
    coef[c] = a;
    coef[128 + c] = beta[c] - mean * a;
    if (zbuf)
        for (int i = c; i < 16384; i += 128) zbuf[i] = 0.f;
}

// mlp1 (fp32, proven)
__global__ __launch_bounds__(256) void k_mlp1(const float* __restrict__ x,
                                              const float* __restrict__ w1,
                                              const float* __restrict__ b1,
                                              const float* __restrict__ w2,
                                              const float* __restrict__ b2,
                                              float* __restrict__ h1, float* __restrict__ st) {
    __shared__ float Xs[64 * 44];
    __shared__ float As[64 * 132];
    int tid = threadIdx.x, tx = tid & 15, ty = tid >> 4;
    int r0 = blockIdx.x * 64;
    for (int idx = tid; idx < 64 * 40; idx += 256) {
        int r = idx / 40, k = idx - r * 40;
        int rr = r0 + r, b = rr >> 6, n = rr & 63, t = k >> 2, d = k & 3;
        Xs[r * 44 + k] = x[((b * 10 + t) * 64 + n) * 4 + d];
    }
    __syncthreads();
    float acc[4][8] = {};
    gemm_globalW(Xs, 44, w1, 40, acc, tx, ty);
    float vals[4][8];
    bias_elu(acc, b1, vals, tx);
    int ca = 4 * tx, cb = 64 + 4 * tx;
#pragma unroll
    for (int j = 0; j < 4; ++j) {
        int r = ty + 16 * j;
#pragma unroll
        for (int u = 0; u < 4; ++u) {
            As[r * 132 + ca + u] = vals[j][u];
            As[r * 132 + cb + u] = vals[j][u + 4];
        }
    }
    __syncthreads();
    float acc2[4][8] = {};
    gemm_globalW(As, 132, w2, 128, acc2, tx, ty);
    float vals2[4][8];
    bias_elu(acc2, b2, vals2, tx);
    store_tile(h1, r0, vals2, tx, ty);
    stats_tail(vals2, As, st + (blockIdx.x & 63) * 256, tid, tx, ty);
}

// P/Q precompute (fp32), 32-row tiles for full-CU coverage. 256 blocks.
__global__ __launch_bounds__(256) void k_pq(const float* __restrict__ h,
                                            const float* __restrict__ coef,
                                            const float* __restrict__ w,
                                            float* __restrict__ P, float* __restrict__ Q) {
    __shared__ float As[32 * 132];
    int tid = threadIdx.x, tx = tid & 15, ty = tid >> 4;
    int half = blockIdx.x >> 7;
    int r0 = (blockIdx.x & 127) * 32;
    const float* Wg = w + half * 128 * 128;
    float* out = half ? Q : P;
    const float4* h4 = (const float4*)h;
    const float4* av = (const float4*)coef;
    const float4* cv = (const float4*)(coef + 128);
#pragma unroll
    for (int i = 0; i < 4; ++i) {
        int f4 = tid + i * 256;
        int r = f4 >> 5, c4 = f4 & 31;
        float4 hv = h4[(r0 + r) * 32 + c4];
        float4 a = av[c4], c = cv[c4];
        float4 v;
        v.x = a.x * hv.x + c.x;
        v.y = a.y * hv.y + c.y;
        v.z = a.z * hv.z + c.z;
        v.w = a.w * hv.w + c.w;
        *(float4*)(As + r * 132 + c4 * 4) = v;
    }
    __syncthreads();
    float acc[2][8] = {};
    const float4* Wg4 = (const float4*)Wg;
#pragma unroll 4
    for (int k = 0; k < 128; ++k) {
        float a0 = As[ty * 132 + k];
        float a1 = As[(ty + 16) * 132 + k];
        float4 wa = Wg4[k * 32 + tx];
        float4 wb = Wg4[k * 32 + 16 + tx];
        const float wv[8] = {wa.x, wa.y, wa.z, wa.w, wb.x, wb.y, wb.z, wb.w};
#pragma unroll
        for (int u = 0; u < 8; ++u) {
            acc[0][u] = fmaf(a0, wv[u], acc[0][u]);
            acc[1][u] = fmaf(a1, wv[u], acc[1][u]);
        }
    }
#pragma unroll
    for (int j = 0; j < 2; ++j) {
        int r = r0 + ty + 16 * j;
        *(float4*)(out + r * 128 + 4 * tx) = make_float4(acc[j][0], acc[j][1], acc[j][2], acc[j][3]);
        *(float4*)(out + r * 128 + 64 + 4 * tx) = make_float4(acc[j][4], acc[j][5], acc[j][6], acc[j][7]);
    }
}

// Recv-major fused mlp2 + edge2node + h2 materialization, TWO recv tiles per
// block (n0=2j, n1=2j+1) sharing weight fragments. 2048 blocks.
__global__ __launch_bounds__(256, 3) void k_mlp2agg(const float* __restrict__ P2,
                                                    const float* __restrict__ Q2,
                                                    const float* __restrict__ b1,
                                                    const _Float16* __restrict__ w2p,
                                                    const float* __restrict__ b2,
                                                    float* __restrict__ aggraw,
                                                    _Float16* __restrict__ h2,
                                                    float* __restrict__ st) {
    __shared__ _Float16 Afr0[8192];  // tile n0; reused as row-major bounce
    __shared__ _Float16 Afr1[8192];  // tile n1
    int tid = threadIdx.x;
    int lane = tid & 63, w = tid >> 6, cl = lane & 15, quad = lane >> 4;
    int b = blockIdx.x >> 5, j2 = blockIdx.x & 31;
    int n0 = 2 * j2, n1 = n0 + 1;
    float* stc = st + (blockIdx.x & 63) * 256;
    {
        int r = lane;
        int s0 = (r < 63) ? (r + (r >= n0 ? 1 : 0)) : n0;  // row 63: dummy
        int s1i = (r < 63) ? (r + (r >= n1 ? 1 : 0)) : n1;
        const float4* B1 = (const float4*)b1;
        stage_pair(Afr0, (const float4*)(P2 + (b * 64 + s0) * 128),
                   (const float4*)(Q2 + (b * 64 + n0) * 128), B1, lane, w);
        stage_pair(Afr1, (const float4*)(P2 + (b * 64 + s1i) * 128),
                   (const float4*)(Q2 + (b * 64 + n1) * 128), B1, lane, w);
    }
    __syncthreads();
    f4v acc0[4][2], acc1[4][2];
#pragma unroll
    for (int rt = 0; rt < 4; ++rt)
#pragma unroll
        for (int c = 0; c < 2; ++c) {
            acc0[rt][c] = (f4v){0.f, 0.f, 0.f, 0.f};
            acc1[rt][c] = (f4v){0.f, 0.f, 0.f, 0.f};
        }
    gemm2_gw(Afr0, Afr1, w2p, acc0, acc1, lane, w);
    // epilogue: bias+elu, mask dummy row 63, per-tile agg + merged stats
    float v0[2][4][4], v1[2][4][4];  // [ctl][rt][i]
#pragma unroll
    for (int ctl = 0; ctl < 2; ++ctl) {
        int col = (w * 2 + ctl) * 16 + cl;
        float bias = b2[col];
        float a0 = 0.f, a1 = 0.f, sq = 0.f;
#pragma unroll
        for (int rt = 0; rt < 4; ++rt)
#pragma unroll
            for (int i = 0; i < 4; ++i) {
                int row = rt * 16 + quad * 4 + i;
                float va = elu_f(acc0[rt][ctl][i] + bias);
                float vb = elu_f(acc1[rt][ctl][i] + bias);
                if (row == 63) { va = 0.f; vb = 0.f; }
                v0[ctl][rt][i] = va;
                v1[ctl][rt][i] = vb;
                a0 += va;
                a1 += vb;
                sq += va * va + vb * vb;
            }
        a0 += __shfl_xor(a0, 16);
        a1 += __shfl_xor(a1, 16);
        sq += __shfl_xor(sq, 16);
        a0 += __shfl_xor(a0, 32);
        a1 += __shfl_xor(a1, 32);
        sq += __shfl_xor(sq, 32);
        if (quad == 0) {
            aggraw[(b * 64 + n0) * 128 + col] = a0;
            aggraw[(b * 64 + n1) * 128 + col] = a1;
            atomicAdd(stc + col, a0 + a1);
            atomicAdd(stc + 128 + col, sq);
        }
    }
    __syncthreads();  // GEMM A-frag reads done; reuse Afr as row-major tiles
    unsigned short* T0 = (unsigned short*)Afr0;
    unsigned short* T1 = (unsigned short*)Afr1;
#pragma unroll
    for (int ctl = 0; ctl < 2; ++ctl) {
        int col = (w * 2 + ctl) * 16 + cl;
#pragma unroll
        for (int rt = 0; rt < 4; ++rt)
#pragma unroll
            for (int i = 0; i < 4; ++i) {
                int row = rt * 16 + quad * 4 + i;
                _Float16 ha = (_Float16)v0[ctl][rt][i];
                _Float16 hb = (_Float16)v1[ctl][rt][i];
                T0[row * 128 + col] = *(unsigned short*)&ha;
                T1[row * 128 + col] = *(unsigned short*)&hb;
            }
    }
    __syncthreads();
    {  // scatter 63 real rows per tile to h2[e], e = s*63 + (s>n ? n : n-1)
        int rr = tid >> 2, cq = tid & 3;
        if (rr < 63) {
            int s0 = rr + (rr >= n0 ? 1 : 0);
            int e0 = s0 * 63 + (s0 > n0 ? n0 : n0 - 1);
            int s1i = rr + (rr >= n1 ? 1 : 0);
            int e1 = s1i * 63 + (s1i > n1 ? n1 : n1 - 1);
            unsigned short* d0 = (unsigned short*)h2 + ((size_t)b * 4032 + e0) * 128;
            unsigned short* d1 = (unsigned short*)h2 + ((size_t)b * 4032 + e1) * 128;
#pragma unroll
            for (int i = 0; i < 4; ++i) {
                int off = cq * 32 + i * 8;
                *(uint4*)(d0 + off) = *(uint4*)&T0[rr * 128 + off];
                *(uint4*)(d1 + off) = *(uint4*)&T1[rr * 128 + off];
            }
        }
    }
}

// prep for mlp4 skip path (proven)
__global__ void k_wcprep(const float* __restrict__ w41, const float* __restrict__ coef2,
                         _Float16* __restrict__ wcp, float* __restrict__ cvec) {
    int k = blockIdx.x, c = threadIdx.x;  // 128 x 128
    float wv = w41[(256 + k) * 128 + c];
    int g = (c >> 4) * 4 + (k >> 5);
    int L = ((k >> 3) & 3) * 16 + (c & 15);
    int j = k & 7;
    wcp[(g * 64 + L) * 8 + j] = (_Float16)(coef2[k] * wv);
    atomicAdd(&cvec[c], coef2[128 + k] * wv);
}

// mlp3 (fp32, proven)
__global__ __launch_bounds__(256) void k_mlp3(const float* __restrict__ raw,
                                              const float* __restrict__ coef2,
                                              const float* __restrict__ w1,
                                              const float* __restrict__ b1,
                                              const float* __restrict__ w2,
                                              const float* __restrict__ b2,
                                              float* __restrict__ h3, float* __restrict__ st) {
    __shared__ float As[64 * 132];
    int tid = threadIdx.x, tx = tid & 15, ty = tid >> 4;
    int r0 = blockIdx.x * 64;
    const float4* in4 = (const float4*)raw;
    const float4* av = (const float4*)coef2;
    const float4* cv = (const float4*)(coef2 + 128);
    const float inv63 = 1.f / 63.f;
#pragma unroll
    for (int i = 0; i < 8; ++i) {
        int f4 = tid + i * 256;
        int r = f4 >> 5, c4 = f4 & 31;
        float4 hv = in4[(r0 + r) * 32 + c4];
        float4 a = av[c4], c = cv[c4];
        float4 v;
        v.x = a.x * hv.x * inv63 + c.x;
        v.y = a.y * hv.y * inv63 + c.y;
        v.z = a.z * hv.z * inv63 + c.z;
        v.w = a.w * hv.w * inv63 + c.w;
        *(float4*)(As + r * 132 + c4 * 4) = v;
    }
    __syncthreads();
    float acc[4][8] = {};
    gemm_globalW(As, 132, w1, 128, acc, tx, ty);
    float vals[4][8];
    bias_elu(acc, b1, vals, tx);
    __syncthreads();
    int ca = 4 * tx, cb = 64 + 4 * tx;
#pragma unroll
    for (int j = 0; j < 4; ++j) {
        int r = ty + 16 * j;
#pragma unroll
        for (int u = 0; u < 4; ++u) {
            As[r * 132 + ca + u] = vals[j][u];
            As[r * 132 + cb + u] = vals[j][u + 4];
        }
    }
    __syncthreads();
    float acc2[4][8] = {};
    gemm_globalW(As, 132, w2, 128, acc2, tx, ty);
    float vals2[4][8];
    bias_elu(acc2, b2, vals2, tx);
    store_tile(h3, r0, vals2, tx, ty);
    stats_tail(vals2, As, st + (blockIdx.x & 63) * 256, tid, tx, ty);
}

// mlp4 edge kernel v3: h2 READ, two tiles/block, fp16 h4, and Q4[b] STAGED IN
// LDS (fp16, stride 136) so ep2's scattered per-row gathers become LDS reads.
// Tile 1 shares the staged block except when it crosses a batch boundary
// (63/2016 blocks) -> block-uniform global fallback.
__global__ __launch_bounds__(256, 3) void k_mlp4r2(const _Float16* __restrict__ h2,
                                                   const float* __restrict__ P4,
                                                   const float* __restrict__ Q4,
                                                   const _Float16* __restrict__ wcp,
                                                   const float* __restrict__ cvec,
                                                   const float* __restrict__ b1,
                                                   const _Float16* __restrict__ w4p2,
                                                   const float* __restrict__ b2,
                                                   unsigned short* __restrict__ h4,
                                                   float* __restrict__ st) {
    __shared__ _Float16 Afr0[8192];     // 16 KB (tile 0; reused as fp16 bounce)
    __shared__ _Float16 Afr1[8192];     // 16 KB (tile 1)
    __shared__ _Float16 Q4s[64 * 136];  // 17 KB: Q4[b0] rows, fp16
    int tid = threadIdx.x;
    int lane = tid & 63, w = tid >> 6, cl = lane & 15, quad = lane >> 4;
    unsigned t0 = 2u * blockIdx.x, t1 = t0 + 1u;
    unsigned b0 = t0 / 63, b1i = t1 / 63;
    unsigned e00 = (t0 - b0 * 63) * 64, e01 = (t1 - b1i * 63) * 64;
    int row00 = t0 * 64, row01 = t1 * 64;
    float* stc = st + (blockIdx.x & 63) * 256;
    // stage h2 tiles: coalesced h8 loads (row-major) -> A-frag LDS
#pragma unroll
    for (int i = 0; i < 4; ++i) {
        int u = tid + i * 256;  // 0..1023
        int r = u >> 4, cu = u & 15;
        int dst = (((r >> 4) * 4 + (cu >> 2)) * 64 + (cu & 3) * 16 + (r & 15)) * 8;
        *(h8*)&Afr0[dst] = *(const h8*)&h2[(size_t)(row00 + r) * 128 + cu * 8];
        *(h8*)&Afr1[dst] = *(const h8*)&h2[(size_t)(row01 + r) * 128 + cu * 8];
    }
    // stage Q4[b0]: 64x128 fp32 coalesced -> fp16 LDS (stride 136)
    {
        const float4* Q4b = (const float4*)(Q4 + (size_t)b0 * 8192);
#pragma unroll
        for (int i = 0; i < 8; ++i) {
            int u = tid + i * 256;  // 0..2047
            int r = u >> 5, c4 = u & 31;
            float4 q = Q4b[r * 32 + c4];
            h4v hq;
            hq[0] = (_Float16)q.x;
            hq[1] = (_Float16)q.y;
            hq[2] = (_Float16)q.z;
            hq[3] = (_Float16)q.w;
            *(h4v*)&Q4s[r * 136 + c4 * 4] = hq;
        }
    }
    __syncthreads();
    f4v acc0[4][2], acc1[4][2];
#pragma unroll
    for (int rt = 0; rt < 4; ++rt)
#pragma unroll
        for (int c = 0; c < 2; ++c) {
            acc0[rt][c] = (f4v){0.f, 0.f, 0.f, 0.f};
            acc1[rt][c] = (f4v){0.f, 0.f, 0.f, 0.f};
        }
    gemm2_gw(Afr0, Afr1, wcp, acc0, acc1, lane, w);
    // ep2: pre1 = elu(acc + P4[s][col] + Q4[rv][col] + b1[col] + cvec[col]).
    // s spans at most {sA, sA+1} per tile -> preload+select; Q4 from LDS.
    float v0[4][2][4], v1[4][2][4];
    {
        int col0 = w * 32 + cl, col1 = col0 + 16;
        float base0 = b1[col0] + cvec[col0];
        float base1 = b1[col1] + cvec[col1];
        unsigned sA0 = e00 / 63, sA1 = e01 / 63;
        unsigned baseE0 = sA0 * 63, baseE1 = sA1 * 63;
        unsigned eB0 = baseE0 + 63, eB1 = baseE1 + 63;
        unsigned sB0 = sA0 < 63u ? sA0 + 1u : sA0;
        unsigned sB1 = sA1 < 63u ? sA1 + 1u : sA1;
        const float* PA0 = P4 + (b0 * 64 + sA0) * 128;
        const float* PB0 = P4 + (b0 * 64 + sB0) * 128;
        const float* PA1 = P4 + (b1i * 64 + sA1) * 128;
        const float* PB1 = P4 + (b1i * 64 + sB1) * 128;
        float pA0c0 = PA0[col0], pA0c1 = PA0[col1];
        float pB0c0 = PB0[col0], pB0c1 = PB0[col1];
        float pA1c0 = PA1[col0], pA1c1 = PA1[col1];
        float pB1c0 = PB1[col0], pB1c1 = PB1[col1];
#pragma unroll
        for (int rt = 0; rt < 4; ++rt)
#pragma unroll
            for (int i = 0; i < 4; ++i) {
                int rr = rt * 16 + quad * 4 + i;
                unsigned e = e00 + rr;
                bool hi = e >= eB0;
                unsigned s = hi ? sB0 : sA0;
                unsigned jj = e - (hi ? eB0 : baseE0);
                unsigned rv = jj + (jj >= s ? 1u : 0u);
                float q0 = (float)Q4s[rv * 136 + col0];
                float q1f = (float)Q4s[rv * 136 + col1];
                float p0 = hi ? pB0c0 : pA0c0, p1 = hi ? pB0c1 : pA0c1;
                v0[rt][0][i] = elu_f(acc0[rt][0][i] + p0 + q0 + base0);
                v0[rt][1][i] = elu_f(acc0[rt][1][i] + p1 + q1f + base1);
            }
        if (b1i == b0) {
#pragma unroll
            for (int rt = 0; rt < 4; ++rt)
#pragma unroll
                for (int i = 0; i < 4; ++i) {
                    int rr = rt * 16 + quad * 4 + i;
                    unsigned e = e01 + rr;
                    bool hi = e >= eB1;
                    unsigned s = hi ? sB1 : sA1;
                    unsigned jj = e - (hi ? eB1 : baseE1);
                    unsigned rv = jj + (jj >= s ? 1u : 0u);
                    float q0 = (float)Q4s[rv * 136 + col0];
                    float q1f = (float)Q4s[rv * 136 + col1];
                    float p0 = hi ? pB1c0 : pA1c0, p1 = hi ? pB1c1 : pA1c1;
                    v1[rt][0][i] = elu_f(acc1[rt][0][i] + p0 + q0 + base0);
                    v1[rt][1][i] = elu_f(acc1[rt][1][i] + p1 + q1f + base1);
                }
        } else {
            const float* Qg1 = Q4 + (size_t)b1i * 8192;
#pragma unroll
            for (int rt = 0; rt < 4; ++rt)
#pragma unroll
                for (int i = 0; i < 4; ++i) {
                    int rr = rt * 16 + quad * 4 + i;
                    unsigned e = e01 + rr;
                    bool hi = e >= eB1;
                    unsigned s = hi ? sB1 : sA1;
                    unsigned jj = e - (hi ? eB1 : baseE1);
                    unsigned rv = jj + (jj >= s ? 1u : 0u);
                    float q0 = Qg1[rv * 128 + col0];
                    float q1f = Qg1[rv * 128 + col1];
                    float p0 = hi ? pB1c0 : pA1c0, p1 = hi ? pB1c1 : pA1c1;
                    v1[rt][0][i] = elu_f(acc1[rt][0][i] + p0 + q0 + base0);
                    v1[rt][1][i] = elu_f(acc1[rt][1][i] + p1 + q1f + base1);
                }
        }
    }
    __syncthreads();
    vals_to_afrag(Afr0, v0, lane, w);
    vals_to_afrag(Afr1, v1, lane, w);
    __syncthreads();
#pragma unroll
    for (int rt = 0; rt < 4; ++rt)
#pragma unroll
        for (int c = 0; c < 2; ++c) {
            acc0[rt][c] = (f4v){0.f, 0.f, 0.f, 0.f};
            acc1[rt][c] = (f4v){0.f, 0.f, 0.f, 0.f};
        }
    gemm2_gw(Afr0, Afr1, w4p2, acc0, acc1, lane, w);
    // ep3: h4 = elu(acc + b2[col]) both tiles; merged column stats
#pragma unroll
    for (int ctl = 0; ctl < 2; ++ctl) {
        int col = (w * 2 + ctl) * 16 + cl;
        float bias = b2[col];
        float s1 = 0.f, s2 = 0.f;
#pragma unroll
        for (int rt = 0; rt < 4; ++rt)
#pragma unroll
            for (int i = 0; i < 4; ++i) {
                float va = elu_f(acc0[rt][ctl][i] + bias);
                float vb = elu_f(acc1[rt][ctl][i] + bias);
                v0[rt][ctl][i] = va;
                v1[rt][ctl][i] = vb;
                s1 += va + vb;
                s2 += va * va + vb * vb;
            }
        s1 += __shfl_xor(s1, 16);
        s2 += __shfl_xor(s2, 16);
        s1 += __shfl_xor(s1, 32);
        s2 += __shfl_xor(s2, 32);
        if (quad == 0) {
            atomicAdd(stc + col, s1);
            atomicAdd(stc + 128 + col, s2);
        }
    }
    __syncthreads();  // GEMM3 A-frag reads done; reuse Afr as fp16 tiles
    unsigned short* T0 = (unsigned short*)Afr0;
    unsigned short* T1 = (unsigned short*)Afr1;
#pragma unroll
    for (int ctl = 0; ctl < 2; ++ctl) {
        int col = (w * 2 + ctl) * 16 + cl;
#pragma unroll
        for (int rt = 0; rt < 4; ++rt)
#pragma unroll
            for (int i = 0; i < 4; ++i) {
                int rr = rt * 16 + quad * 4 + i;
                _Float16 ha = (_Float16)v0[rt][ctl][i];
                _Float16 hb = (_Float16)v1[rt][ctl][i];
                T0[rr * 128 + col] = *(unsigned short*)&ha;
                T1[rr * 128 + col] = *(unsigned short*)&hb;
            }
    }
    __syncthreads();
    {
        int rr = tid >> 2, cq = tid & 3;
#pragma unroll
        for (int i = 0; i < 4; ++i) {
            int off = rr * 128 + cq * 32 + i * 8;
            *(uint4*)(h4 + (size_t)row00 * 128 + off) = *(uint4*)&T0[off];
            *(uint4*)(h4 + (size_t)row01 * 128 + off) = *(uint4*)&T1[off];
        }
    }
}

// final: out[row,k] = sum_c (a4[c]*h4[row,c]+shift4[c]) * fcw[c,k] + fcb[k]
// h4 is fp16.
__global__ __launch_bounds__(256) void k_out(const unsigned short* __restrict__ h4,
                                             const float* __restrict__ coef4,
                                             const float* __restrict__ fcw,
                                             const float* __restrict__ fcb,
                                             float* __restrict__ out) {
    int tid = threadIdx.x;
    int lane = tid & 31, rsub = tid >> 5;
    int row = blockIdx.x * 8 + rsub;
    h4v hv = ((const h4v*)(h4 + (size_t)row * 128))[lane];
    float x0 = (float)hv[0], x1 = (float)hv[1], x2 = (float)hv[2], x3 = (float)hv[3];
    float4 a = ((const float4*)coef4)[lane];
    float4 c = ((const float4*)(coef4 + 128))[lane];
    x0 = a.x * x0 + c.x;
    x1 = a.y * x1 + c.y;
    x2 = a.z * x2 + c.z;
    x3 = a.w * x3 + c.w;
    const float4* W = (const float4*)(fcw + lane * 8);
    float4 w01 = W[0], w23 = W[1];
    float s0 = x0 * w01.x + x1 * w01.z + x2 * w23.x + x3 * w23.z;
    float s1 = x0 * w01.y + x1 * w01.w + x2 * w23.y + x3 * w23.w;
#pragma unroll
    for (int off = 16; off > 0; off >>= 1) {
        s0 += __shfl_down(s0, off, 32);
        s1 += __shfl_down(s1, off, 32);
    }
    if (lane == 0) {
        out[row * 2] = s0 + fcb[0];
        out[row * 2 + 1] = s1 + fcb[1];
    }
}

// ---------------------------------------------------------------------------

extern "C" void kernel_launch(void* const* d_in, const int* in_sizes, int n_in,
                              void* d_out, int out_size, void* d_ws, size_t ws_size,
                              hipStream_t stream) {
    const float* x = (const float*)d_in[0];
    const float* m1_w1 = (const float*)d_in[1];
    const float* m1_b1 = (const float*)d_in[2];
    const float* m1_w2 = (const float*)d_in[3];
    const float* m1_b2 = (const float*)d_in[4];
    const float* m1_g = (const float*)d_in[5];
    const float* m1_be = (const float*)d_in[6];
    const float* m2_w1 = (const float*)d_in[7];
    const float* m2_b1 = (const float*)d_in[8];
    const float* m2_w2 = (const float*)d_in[9];
    const float* m2_b2 = (const float*)d_in[10];
    const float* m2_g = (const float*)d_in[11];
    const float* m2_be = (const float*)d_in[12];
    const float* m3_w1 = (const float*)d_in[13];
    const float* m3_b1 = (const float*)d_in[14];
    const float* m3_w2 = (const float*)d_in[15];
    const float* m3_b2 = (const float*)d_in[16];
    const float* m3_g = (const float*)d_in[17];
    const float* m3_be = (const float*)d_in[18];
    const float* m4_w1 = (const float*)d_in[19];
    const float* m4_b1 = (const float*)d_in[20];
    const float* m4_w2 = (const float*)d_in[21];
    const float* m4_b2 = (const float*)d_in[22];
    const float* m4_g = (const float*)d_in[23];
    const float* m4_be = (const float*)d_in[24];
    const float* fc_w = (const float*)d_in[25];
    const float* fc_b = (const float*)d_in[26];
    float* out = (float*)d_out;

    float* W = (float*)d_ws;
    float* coef1 = W + OFF_COEF;
    float* coef2 = W + OFF_COEF + 256;
    float* coef3 = W + OFF_COEF + 512;
    float* coef4 = W + OFF_COEF + 768;
    float* cvec = W + OFF_CVEC;
    float* h1 = W + OFF_H1;        // aliased: aggraw; sums4 = h1[0:16384)
    float* aggraw = h1;
    float* sums4 = h1;
    float* P2 = W + OFF_P2;        // sums1 = P2[0:16384)
    float* sums1 = P2;
    float* Q2 = W + OFF_Q2;
    float* h3 = W + OFF_H3;
    float* P4 = W + OFF_P4;        // sums2 = P4[0:16384)
    float* sums2 = P4;
    float* Q4 = W + OFF_Q4;        // sums3 = Q4[0:16384)
    float* sums3 = Q4;
    _Float16* w2p2 = (_Float16*)(W + OFF_W2P);
    _Float16* w4p2 = (_Float16*)(W + OFF_W4P);
    _Float16* wcp = (_Float16*)(W + OFF_WCP);
    _Float16* h2f = (_Float16*)(W + OFF_H4B);             // h2 (fp16), then
    unsigned short* h4b = (unsigned short*)(W + OFF_H4B); // h4 (fp16) in place

    if (ws_size < WS_BYTES) return;  // safe-fail diagnostic (no OOB fault)

    k_prep<<<209, 256, 0, stream>>>(W, m2_w2, m4_w2);
    k_mlp1<<<64, 256, 0, stream>>>(x, m1_w1, m1_b1, m1_w2, m1_b2, h1, sums1);
    k_finalize<<<1, 128, 0, stream>>>(sums1, coef1, 1.f / 4096.f, m1_g, m1_be, nullptr);
    k_pq<<<256, 256, 0, stream>>>(h1, coef1, m2_w1, P2, Q2);
    k_mlp2agg<<<2048, 256, 0, stream>>>(P2, Q2, m2_b1, w2p2, m2_b2, aggraw, h2f, sums2);
    k_finalize<<<1, 128, 0, stream>>>(sums2, coef2, 1.f / 258048.f, m2_g, m2_be, nullptr);
    k_wcprep<<<128, 128, 0, stream>>>(m4_w1, coef2, wcp, cvec);
    k_mlp3<<<64, 256, 0, stream>>>(aggraw, coef2, m3_w1, m3_b1, m3_w2, m3_b2, h3, sums3);
    k_finalize<<<1, 128, 0, stream>>>(sums3, coef3, 1.f / 4096.f, m3_g, m3_be, sums4);
    k_pq<<<256, 256, 0, stream>>>(h3, coef3, m4_w1, P4, Q4);
    k_mlp4r2<<<2016, 256, 0, stream>>>(h2f, P4, Q4, wcp, cvec, m4_b1, w4p2, m4_b2,
                                       h4b, sums4);
    k_finalize<<<1, 128, 0, stream>>>(sums4, coef4, 1.f / 258048.f, m4_g, m4_be, nullptr);
    k_out<<<32256, 256, 0, stream>>>(h4b, coef4, fc_w, fc_b, out);
}

// Round 14
// 346.438 us; speedup vs baseline: 1.0186x; 1.0186x over previous
//
#include <hip/hip_runtime.h>

#define BN_EPS 1e-5f

using h8 = __attribute__((ext_vector_type(8))) _Float16;
using h4v = __attribute__((ext_vector_type(4))) _Float16;
using f4v = __attribute__((ext_vector_type(4))) float;

// workspace float offsets (proven layout)
#define OFF_COEF 0        // 4 stages x 256 (a @ [0:128), shift @ [128:256))
#define OFF_CVEC 1024     // 128
#define OFF_H1 4096       // 4096x128 (aliased: aggraw; first 16384 = sums4)
#define OFF_P2 528384     // first 16384 floats = sums1 (dead until k_pq1)
#define OFF_Q2 1052672
#define OFF_H3 1576960
#define OFF_P4 2101248    // first 16384 = sums2 (dead until k_pq4)
#define OFF_Q4 2625536    // first 16384 = sums3 (dead until k_pq4)
#define OFF_W2P 3149824   // 16384 fp16 = 8192 floats each
#define OFF_W4P 3158016
#define OFF_WCP 3166208
#define OFF_H4B 3174400   // 258048x128 fp16: h2 then h4 in place
#define WS_BYTES 78757888ull

__device__ __forceinline__ float elu_f(float x) {
    return x > 0.f ? x : __expf(x) - 1.f;
}

// ---------------------------------------------------------------------------
// fp32 tile GEMM helpers (node-level kernels, 32-row tiles).
// ---------------------------------------------------------------------------

__device__ __forceinline__ void gemm32_globalW(const float* As, int lda,
                                               const float* __restrict__ Wg, int K,
                                               float acc[2][8], int tx, int ty) {
    const float4* Wg4 = (const float4*)Wg;
#pragma unroll 4
    for (int k = 0; k < K; ++k) {
        float a0 = As[ty * lda + k];
        float a1 = As[(ty + 16) * lda + k];
        float4 wa = Wg4[k * 32 + tx];
        float4 wb = Wg4[k * 32 + 16 + tx];
        const float wv[8] = {wa.x, wa.y, wa.z, wa.w, wb.x, wb.y, wb.z, wb.w};
#pragma unroll
        for (int u = 0; u < 8; ++u) {
            acc[0][u] = fmaf(a0, wv[u], acc[0][u]);
            acc[1][u] = fmaf(a1, wv[u], acc[1][u]);
        }
    }
}

__device__ __forceinline__ void bias_elu32(const float acc[2][8],
                                           const float* __restrict__ bias,
                                           float vals[2][8], int tx) {
    int ca = 4 * tx, cb = 64 + 4 * tx;
    float bv[8] = {bias[ca], bias[ca + 1], bias[ca + 2], bias[ca + 3],
                   bias[cb], bias[cb + 1], bias[cb + 2], bias[cb + 3]};
#pragma unroll
    for (int j = 0; j < 2; ++j)
#pragma unroll
        for (int u = 0; u < 8; ++u)
            vals[j][u] = elu_f(acc[j][u] + bv[u]);
}

__device__ __forceinline__ void store_tile32(float* __restrict__ out, int row0,
                                             const float vals[2][8], int tx, int ty) {
#pragma unroll
    for (int j = 0; j < 2; ++j) {
        int r = row0 + ty + 16 * j;
        *(float4*)(out + r * 128 + 4 * tx) =
            make_float4(vals[j][0], vals[j][1], vals[j][2], vals[j][3]);
        *(float4*)(out + r * 128 + 64 + 4 * tx) =
            make_float4(vals[j][4], vals[j][5], vals[j][6], vals[j][7]);
    }
}

// 32-row stats: 2-row partials, same 16x128 red reduction shape as before.
__device__ __forceinline__ void stats_tail32(const float vals[2][8], float* red,
                                             float* __restrict__ st, int tid, int tx, int ty) {
    float ls[8], lq[8];
#pragma unroll
    for (int u = 0; u < 8; ++u) {
        ls[u] = vals[0][u] + vals[1][u];
        lq[u] = vals[0][u] * vals[0][u] + vals[1][u] * vals[1][u];
    }
    __syncthreads();
    int ca = 4 * tx, cb = 64 + 4 * tx;
#pragma unroll
    for (int u = 0; u < 4; ++u) {
        red[ty * 128 + ca + u] = ls[u];
        red[2048 + ty * 128 + ca + u] = lq[u];
        red[ty * 128 + cb + u] = ls[u + 4];
        red[2048 + ty * 128 + cb + u] = lq[u + 4];
    }
    __syncthreads();
    if (tid < 128) {
        float s = 0.f, q = 0.f;
#pragma unroll
        for (int t = 0; t < 16; ++t) {
            s += red[t * 128 + tid];
            q += red[2048 + t * 128 + tid];
        }
        atomicAdd(st + tid, s);
        atomicAdd(st + 128 + tid, q);
    }
}

// ---------------------------------------------------------------------------
// MFMA helpers (proven). A-frag LDS layout:
// Afr[((rt*4+kc)*64 + o*16 + m)*8 + j] = act[rt*16+m][kc*32+o*8+j] (fp16).
// Weights prepacked in GLOBAL: Wp[((ct*4+kc)*64+L)*8+j] =
// W[kc*32+(L>>4)*8+j][ct*16+(L&15)]. Wave w computes rows 0..63 x cols
// [32w, 32w+32). gemm2_gw: one weight-frag load feeds BOTH tiles' MFMAs.
// ---------------------------------------------------------------------------

__device__ __forceinline__ void gemm2_gw(const _Float16* A0, const _Float16* A1,
                                         const _Float16* __restrict__ wp,
                                         f4v acc0[4][2], f4v acc1[4][2], int lane, int w) {
#pragma unroll
    for (int kc = 0; kc < 4; ++kc) {
        h8 bf0 = *(const h8*)&wp[(((w * 2 + 0) * 4 + kc) * 64 + lane) * 8];
        h8 bf1 = *(const h8*)&wp[(((w * 2 + 1) * 4 + kc) * 64 + lane) * 8];
        h8 af0[4], af1[4];
#pragma unroll
        for (int rt = 0; rt < 4; ++rt) {
            af0[rt] = *(const h8*)&A0[((rt * 4 + kc) * 64 + lane) * 8];
            af1[rt] = *(const h8*)&A1[((rt * 4 + kc) * 64 + lane) * 8];
        }
#pragma unroll
        for (int rt = 0; rt < 4; ++rt) {
            acc0[rt][0] = __builtin_amdgcn_mfma_f32_16x16x32_f16(af0[rt], bf0, acc0[rt][0], 0, 0, 0);
            acc1[rt][0] = __builtin_amdgcn_mfma_f32_16x16x32_f16(af1[rt], bf0, acc1[rt][0], 0, 0, 0);
        }
#pragma unroll
        for (int rt = 0; rt < 4; ++rt) {
            acc0[rt][1] = __builtin_amdgcn_mfma_f32_16x16x32_f16(af0[rt], bf1, acc0[rt][1], 0, 0, 0);
            acc1[rt][1] = __builtin_amdgcn_mfma_f32_16x16x32_f16(af1[rt], bf1, acc1[rt][1], 0, 0, 0);
        }
    }
}

__device__ __forceinline__ void vals_to_afrag(_Float16* Afr, const float vals[4][2][4],
                                              int lane, int w) {
    int cl = lane & 15, quad = lane >> 4;
#pragma unroll
    for (int ctl = 0; ctl < 2; ++ctl) {
        int col = (w * 2 + ctl) * 16 + cl;
        int kc = col >> 5, o = (col >> 3) & 3, j = col & 7;
#pragma unroll
        for (int rt = 0; rt < 4; ++rt)
#pragma unroll
            for (int i = 0; i < 4; ++i) {
                int m = quad * 4 + i;
                Afr[((rt * 4 + kc) * 64 + o * 16 + m) * 8 + j] = (_Float16)vals[rt][ctl][i];
            }
    }
}

// stage A = elu(P[row] + Q[row] + bias) into A-frag layout (proven)
__device__ __forceinline__ void stage_pair(_Float16* Afr, const float4* __restrict__ Pr,
                                           const float4* __restrict__ Qr,
                                           const float4* __restrict__ B1, int lane, int kc) {
    int rt = lane >> 4, m = lane & 15;
#pragma unroll
    for (int o = 0; o < 4; ++o) {
        int c4 = kc * 8 + o * 2;
        float4 p0 = Pr[c4], q0 = Qr[c4], bb0 = B1[c4];
        float4 p1 = Pr[c4 + 1], q1 = Qr[c4 + 1], bb1 = B1[c4 + 1];
        h8 v;
        v[0] = (_Float16)elu_f(p0.x + q0.x + bb0.x);
        v[1] = (_Float16)elu_f(p0.y + q0.y + bb0.y);
        v[2] = (_Float16)elu_f(p0.z + q0.z + bb0.z);
        v[3] = (_Float16)elu_f(p0.w + q0.w + bb0.w);
        v[4] = (_Float16)elu_f(p1.x + q1.x + bb1.x);
        v[5] = (_Float16)elu_f(p1.y + q1.y + bb1.y);
        v[6] = (_Float16)elu_f(p1.z + q1.z + bb1.z);
        v[7] = (_Float16)elu_f(p1.w + q1.w + bb1.w);
        *(h8*)&Afr[((rt * 4 + kc) * 64 + o * 16 + m) * 8] = v;
    }
}

// ---------------------------------------------------------------------------
// Kernels
// ---------------------------------------------------------------------------

// merged: zero shadow-sum arenas + cvec; pack w2/w4 layer-2 weights to fp16 frag
__global__ void k_prep(float* W, const float* __restrict__ w2src,
                       const float* __restrict__ w4src) {
    int blk = blockIdx.x, tid = threadIdx.x;
    if (blk < 193) {
        int i = blk * 256 + tid;
        if (i < 16384) W[OFF_P2 + i] = 0.f;
        else if (i < 32768) W[OFF_P4 + i - 16384] = 0.f;
        else if (i < 49152) W[OFF_Q4 + i - 32768] = 0.f;
        else if (i < 49280) W[OFF_CVEC + i - 49152] = 0.f;
    } else {
        int second = blk >= 201;
        const float* src = second ? w4src : w2src;
        _Float16* wp = (_Float16*)(W + (second ? OFF_W4P : OFF_W2P));
        int flat = (blk - (second ? 201 : 193)) * 256 + tid;  // 0..2047
        int g = flat >> 6, L = flat & 63;
        int ct = g >> 2, kc = g & 3;
        int nn = ct * 16 + (L & 15), k0 = kc * 32 + (L >> 4) * 8;
        h8 v;
#pragma unroll
        for (int j = 0; j < 8; ++j) v[j] = (_Float16)src[(k0 + j) * 128 + nn];
        *(h8*)&wp[flat * 8] = v;
    }
}

__global__ void k_finalize(const float* __restrict__ sums, float* __restrict__ coef,
                           float invM, const float* __restrict__ g,
                           const float* __restrict__ beta, float* __restrict__ zbuf) {
    int c = threadIdx.x;  // 128
    float s = 0.f, q = 0.f;
#pragma unroll 8
    for (int t = 0; t < 64; ++t) {
        s += sums[t * 256 + c];
        q += sums[t * 256 + 128 + c];
    }
    float mean = s * invM;
    float var = q * invM - mean * mean;
    float a = g[c] * rsqrtf(var + BN_EPS);
    coef[c] = a;
    coef[128 + c] = beta[c] - mean * a;
    if (zbuf)
        for (int i = c; i < 16384; i += 128) zbuf[i] = 0.f;
}

// mlp1: 32-row tiles, 128 blocks. K1 = 40 (transposed input gather), K2 = 128.
__global__ __launch_bounds__(256) void k_mlp1(const float* __restrict__ x,
                                              const float* __restrict__ w1,
                                              const float* __restrict__ b1,
                                              const float* __restrict__ w2,
                                              const float* __restrict__ b2,
                                              float* __restrict__ h1, float* __restrict__ st) {
    __shared__ float Xs[32 * 44];
    __shared__ float As[32 * 132];
    int tid = threadIdx.x, tx = tid & 15, ty = tid >> 4;
    int r0 = blockIdx.x * 32;
    for (int idx = tid; idx < 32 * 40; idx += 256) {
        int r = idx / 40, k = idx - r * 40;
        int rr = r0 + r, b = rr >> 6, n = rr & 63, t = k >> 2, d = k & 3;
        Xs[r * 44 + k] = x[((b * 10 + t) * 64 + n) * 4 + d];
    }
    __syncthreads();
    float acc[2][8] = {};
    gemm32_globalW(Xs, 44, w1, 40, acc, tx, ty);
    float vals[2][8];
    bias_elu32(acc, b1, vals, tx);
    int ca = 4 * tx, cb = 64 + 4 * tx;
#pragma unroll
    for (int j = 0; j < 2; ++j) {
        int r = ty + 16 * j;
#pragma unroll
        for (int u = 0; u < 4; ++u) {
            As[r * 132 + ca + u] = vals[j][u];
            As[r * 132 + cb + u] = vals[j][u + 4];
        }
    }
    __syncthreads();
    float acc2[2][8] = {};
    gemm32_globalW(As, 132, w2, 128, acc2, tx, ty);
    float vals2[2][8];
    bias_elu32(acc2, b2, vals2, tx);
    store_tile32(h1, r0, vals2, tx, ty);
    stats_tail32(vals2, As, st + (blockIdx.x & 63) * 256, tid, tx, ty);
}

// P/Q precompute (fp32), 32-row tiles. 256 blocks.
__global__ __launch_bounds__(256) void k_pq(const float* __restrict__ h,
                                            const float* __restrict__ coef,
                                            const float* __restrict__ w,
                                            float* __restrict__ P, float* __restrict__ Q) {
    __shared__ float As[32 * 132];
    int tid = threadIdx.x, tx = tid & 15, ty = tid >> 4;
    int half = blockIdx.x >> 7;
    int r0 = (blockIdx.x & 127) * 32;
    const float* Wg = w + half * 128 * 128;
    float* out = half ? Q : P;
    const float4* h4 = (const float4*)h;
    const float4* av = (const float4*)coef;
    const float4* cv = (const float4*)(coef + 128);
#pragma unroll
    for (int i = 0; i < 4; ++i) {
        int f4 = tid + i * 256;
        int r = f4 >> 5, c4 = f4 & 31;
        float4 hv = h4[(r0 + r) * 32 + c4];
        float4 a = av[c4], c = cv[c4];
        float4 v;
        v.x = a.x * hv.x + c.x;
        v.y = a.y * hv.y + c.y;
        v.z = a.z * hv.z + c.z;
        v.w = a.w * hv.w + c.w;
        *(float4*)(As + r * 132 + c4 * 4) = v;
    }
    __syncthreads();
    float acc[2][8] = {};
    gemm32_globalW(As, 132, Wg, 128, acc, tx, ty);
#pragma unroll
    for (int j = 0; j < 2; ++j) {
        int r = r0 + ty + 16 * j;
        *(float4*)(out + r * 128 + 4 * tx) = make_float4(acc[j][0], acc[j][1], acc[j][2], acc[j][3]);
        *(float4*)(out + r * 128 + 64 + 4 * tx) = make_float4(acc[j][4], acc[j][5], acc[j][6], acc[j][7]);
    }
}

// Recv-major fused mlp2 + edge2node + h2 materialization, TWO recv tiles per
// block (n0=2j, n1=2j+1) sharing weight fragments. 2048 blocks.
__global__ __launch_bounds__(256, 3) void k_mlp2agg(const float* __restrict__ P2,
                                                    const float* __restrict__ Q2,
                                                    const float* __restrict__ b1,
                                                    const _Float16* __restrict__ w2p,
                                                    const float* __restrict__ b2,
                                                    float* __restrict__ aggraw,
                                                    _Float16* __restrict__ h2,
                                                    float* __restrict__ st) {
    __shared__ _Float16 Afr0[8192];  // tile n0; reused as row-major bounce
    __shared__ _Float16 Afr1[8192];  // tile n1
    int tid = threadIdx.x;
    int lane = tid & 63, w = tid >> 6, cl = lane & 15, quad = lane >> 4;
    int b = blockIdx.x >> 5, j2 = blockIdx.x & 31;
    int n0 = 2 * j2, n1 = n0 + 1;
    float* stc = st + (blockIdx.x & 63) * 256;
    {
        int r = lane;
        int s0 = (r < 63) ? (r + (r >= n0 ? 1 : 0)) : n0;  // row 63: dummy
        int s1i = (r < 63) ? (r + (r >= n1 ? 1 : 0)) : n1;
        const float4* B1 = (const float4*)b1;
        stage_pair(Afr0, (const float4*)(P2 + (b * 64 + s0) * 128),
                   (const float4*)(Q2 + (b * 64 + n0) * 128), B1, lane, w);
        stage_pair(Afr1, (const float4*)(P2 + (b * 64 + s1i) * 128),
                   (const float4*)(Q2 + (b * 64 + n1) * 128), B1, lane, w);
    }
    __syncthreads();
    f4v acc0[4][2], acc1[4][2];
#pragma unroll
    for (int rt = 0; rt < 4; ++rt)
#pragma unroll
        for (int c = 0; c < 2; ++c) {
            acc0[rt][c] = (f4v){0.f, 0.f, 0.f, 0.f};
            acc1[rt][c] = (f4v){0.f, 0.f, 0.f, 0.f};
        }
    gemm2_gw(Afr0, Afr1, w2p, acc0, acc1, lane, w);
    // epilogue: bias+elu, mask dummy row 63, per-tile agg + merged stats
    float v0[2][4][4], v1[2][4][4];  // [ctl][rt][i]
#pragma unroll
    for (int ctl = 0; ctl < 2; ++ctl) {
        int col = (w * 2 + ctl) * 16 + cl;
        float bias = b2[col];
        float a0 = 0.f, a1 = 0.f, sq = 0.f;
#pragma unroll
        for (int rt = 0; rt < 4; ++rt)
#pragma unroll
            for (int i = 0; i < 4; ++i) {
                int row = rt * 16 + quad * 4 + i;
                float va = elu_f(acc0[rt][ctl][i] + bias);
                float vb = elu_f(acc1[rt][ctl][i] + bias);
                if (row == 63) { va = 0.f; vb = 0.f; }
                v0[ctl][rt][i] = va;
                v1[ctl][rt][i] = vb;
                a0 += va;
                a1 += vb;
                sq += va * va + vb * vb;
            }
        a0 += __shfl_xor(a0, 16);
        a1 += __shfl_xor(a1, 16);
        sq += __shfl_xor(sq, 16);
        a0 += __shfl_xor(a0, 32);
        a1 += __shfl_xor(a1, 32);
        sq += __shfl_xor(sq, 32);
        if (quad == 0) {
            aggraw[(b * 64 + n0) * 128 + col] = a0;
            aggraw[(b * 64 + n1) * 128 + col] = a1;
            atomicAdd(stc + col, a0 + a1);
            atomicAdd(stc + 128 + col, sq);
        }
    }
    __syncthreads();  // GEMM A-frag reads done; reuse Afr as row-major tiles
    unsigned short* T0 = (unsigned short*)Afr0;
    unsigned short* T1 = (unsigned short*)Afr1;
#pragma unroll
    for (int ctl = 0; ctl < 2; ++ctl) {
        int col = (w * 2 + ctl) * 16 + cl;
#pragma unroll
        for (int rt = 0; rt < 4; ++rt)
#pragma unroll
            for (int i = 0; i < 4; ++i) {
                int row = rt * 16 + quad * 4 + i;
                _Float16 ha = (_Float16)v0[ctl][rt][i];
                _Float16 hb = (_Float16)v1[ctl][rt][i];
                T0[row * 128 + col] = *(unsigned short*)&ha;
                T1[row * 128 + col] = *(unsigned short*)&hb;
            }
    }
    __syncthreads();
    {  // scatter 63 real rows per tile to h2[e], e = s*63 + (s>n ? n : n-1)
        int rr = tid >> 2, cq = tid & 3;
        if (rr < 63) {
            int s0 = rr + (rr >= n0 ? 1 : 0);
            int e0 = s0 * 63 + (s0 > n0 ? n0 : n0 - 1);
            int s1i = rr + (rr >= n1 ? 1 : 0);
            int e1 = s1i * 63 + (s1i > n1 ? n1 : n1 - 1);
            unsigned short* d0 = (unsigned short*)h2 + ((size_t)b * 4032 + e0) * 128;
            unsigned short* d1 = (unsigned short*)h2 + ((size_t)b * 4032 + e1) * 128;
#pragma unroll
            for (int i = 0; i < 4; ++i) {
                int off = cq * 32 + i * 8;
                *(uint4*)(d0 + off) = *(uint4*)&T0[rr * 128 + off];
                *(uint4*)(d1 + off) = *(uint4*)&T1[rr * 128 + off];
            }
        }
    }
}

// prep for mlp4 skip path (proven)
__global__ void k_wcprep(const float* __restrict__ w41, const float* __restrict__ coef2,
                         _Float16* __restrict__ wcp, float* __restrict__ cvec) {
    int k = blockIdx.x, c = threadIdx.x;  // 128 x 128
    float wv = w41[(256 + k) * 128 + c];
    int g = (c >> 4) * 4 + (k >> 5);
    int L = ((k >> 3) & 3) * 16 + (c & 15);
    int j = k & 7;
    wcp[(g * 64 + L) * 8 + j] = (_Float16)(coef2[k] * wv);
    atomicAdd(&cvec[c], coef2[128 + k] * wv);
}

// mlp3: 32-row tiles, 128 blocks. input = a2*(aggraw/63)+shift2, K=128 both.
__global__ __launch_bounds__(256) void k_mlp3(const float* __restrict__ raw,
                                              const float* __restrict__ coef2,
                                              const float* __restrict__ w1,
                                              const float* __restrict__ b1,
                                              const float* __restrict__ w2,
                                              const float* __restrict__ b2,
                                              float* __restrict__ h3, float* __restrict__ st) {
    __shared__ float As[32 * 132];
    int tid = threadIdx.x, tx = tid & 15, ty = tid >> 4;
    int r0 = blockIdx.x * 32;
    const float4* in4 = (const float4*)raw;
    const float4* av = (const float4*)coef2;
    const float4* cv = (const float4*)(coef2 + 128);
    const float inv63 = 1.f / 63.f;
#pragma unroll
    for (int i = 0; i < 4; ++i) {
        int f4 = tid + i * 256;
        int r = f4 >> 5, c4 = f4 & 31;
        float4 hv = in4[(r0 + r) * 32 + c4];
        float4 a = av[c4], c = cv[c4];
        float4 v;
        v.x = a.x * hv.x * inv63 + c.x;
        v.y = a.y * hv.y * inv63 + c.y;
        v.z = a.z * hv.z * inv63 + c.z;
        v.w = a.w * hv.w * inv63 + c.w;
        *(float4*)(As + r * 132 + c4 * 4) = v;
    }
    __syncthreads();
    float acc[2][8] = {};
    gemm32_globalW(As, 132, w1, 128, acc, tx, ty);
    float vals[2][8];
    bias_elu32(acc, b1, vals, tx);
    __syncthreads();  // all reads of As done before overwrite
    int ca = 4 * tx, cb = 64 + 4 * tx;
#pragma unroll
    for (int j = 0; j < 2; ++j) {
        int r = ty + 16 * j;
#pragma unroll
        for (int u = 0; u < 4; ++u) {
            As[r * 132 + ca + u] = vals[j][u];
            As[r * 132 + cb + u] = vals[j][u + 4];
        }
    }
    __syncthreads();
    float acc2[2][8] = {};
    gemm32_globalW(As, 132, w2, 128, acc2, tx, ty);
    float vals2[2][8];
    bias_elu32(acc2, b2, vals2, tx);
    store_tile32(h3, r0, vals2, tx, ty);
    stats_tail32(vals2, As, st + (blockIdx.x & 63) * 256, tid, tx, ty);
}

// mlp4 edge kernel (round-12 proven): h2 READ, two tiles/block, fp16 h4.
// ep2: tile-level send resolution (s spans <=2 values per 64-edge tile) ->
// P4 terms become preload+select; Q4 gathers keep per-row rv (global).
__global__ __launch_bounds__(256, 3) void k_mlp4r2(const _Float16* __restrict__ h2,
                                                   const float* __restrict__ P4,
                                                   const float* __restrict__ Q4,
                                                   const _Float16* __restrict__ wcp,
                                                   const float* __restrict__ cvec,
                                                   const float* __restrict__ b1,
                                                   const _Float16* __restrict__ w4p2,
                                                   const float* __restrict__ b2,
                                                   unsigned short* __restrict__ h4,
                                                   float* __restrict__ st) {
    __shared__ _Float16 Afr0[8192];  // 16 KB (tile 0; reused as fp16 bounce)
    __shared__ _Float16 Afr1[8192];  // 16 KB (tile 1)
    int tid = threadIdx.x;
    int lane = tid & 63, w = tid >> 6, cl = lane & 15, quad = lane >> 4;
    unsigned t0 = 2u * blockIdx.x, t1 = t0 + 1u;
    unsigned b0 = t0 / 63, b1i = t1 / 63;
    unsigned e00 = (t0 - b0 * 63) * 64, e01 = (t1 - b1i * 63) * 64;
    int row00 = t0 * 64, row01 = t1 * 64;
    float* stc = st + (blockIdx.x & 63) * 256;
    // stage h2 tiles: coalesced h8 loads (row-major) -> A-frag LDS
#pragma unroll
    for (int i = 0; i < 4; ++i) {
        int u = tid + i * 256;  // 0..1023
        int r = u >> 4, cu = u & 15;
        int dst = (((r >> 4) * 4 + (cu >> 2)) * 64 + (cu & 3) * 16 + (r & 15)) * 8;
        *(h8*)&Afr0[dst] = *(const h8*)&h2[(size_t)(row00 + r) * 128 + cu * 8];
        *(h8*)&Afr1[dst] = *(const h8*)&h2[(size_t)(row01 + r) * 128 + cu * 8];
    }
    __syncthreads();
    f4v acc0[4][2], acc1[4][2];
#pragma unroll
    for (int rt = 0; rt < 4; ++rt)
#pragma unroll
        for (int c = 0; c < 2; ++c) {
            acc0[rt][c] = (f4v){0.f, 0.f, 0.f, 0.f};
            acc1[rt][c] = (f4v){0.f, 0.f, 0.f, 0.f};
        }
    gemm2_gw(Afr0, Afr1, wcp, acc0, acc1, lane, w);
    // ep2: pre1 = elu(acc + P4[s][col] + Q4[rv][col] + b1[col] + cvec[col]).
    float v0[4][2][4], v1[4][2][4];
    {
        int col0 = w * 32 + cl, col1 = col0 + 16;
        float base0 = b1[col0] + cvec[col0];
        float base1 = b1[col1] + cvec[col1];
        unsigned sA0 = e00 / 63, sA1 = e01 / 63;
        unsigned baseE0 = sA0 * 63, baseE1 = sA1 * 63;
        unsigned eB0 = baseE0 + 63, eB1 = baseE1 + 63;
        unsigned sB0 = sA0 < 63u ? sA0 + 1u : sA0;
        unsigned sB1 = sA1 < 63u ? sA1 + 1u : sA1;
        const float* PA0 = P4 + (b0 * 64 + sA0) * 128;
        const float* PB0 = P4 + (b0 * 64 + sB0) * 128;
        const float* PA1 = P4 + (b1i * 64 + sA1) * 128;
        const float* PB1 = P4 + (b1i * 64 + sB1) * 128;
        float pA0c0 = PA0[col0], pA0c1 = PA0[col1];
        float pB0c0 = PB0[col0], pB0c1 = PB0[col1];
        float pA1c0 = PA1[col0], pA1c1 = PA1[col1];
        float pB1c0 = PB1[col0], pB1c1 = PB1[col1];
        const float* Qb0 = Q4 + (size_t)b0 * 8192;
        const float* Qb1 = Q4 + (size_t)b1i * 8192;
#pragma unroll
        for (int rt = 0; rt < 4; ++rt)
#pragma unroll
            for (int i = 0; i < 4; ++i) {
                int rr = rt * 16 + quad * 4 + i;
                {
                    unsigned e = e00 + rr;
                    bool hi = e >= eB0;
                    unsigned s = hi ? sB0 : sA0;
                    unsigned jj = e - (hi ? eB0 : baseE0);
                    unsigned rv = jj + (jj >= s ? 1u : 0u);
                    const float* Qr = Qb0 + rv * 128;
                    float p0 = hi ? pB0c0 : pA0c0, p1 = hi ? pB0c1 : pA0c1;
                    v0[rt][0][i] = elu_f(acc0[rt][0][i] + p0 + Qr[col0] + base0);
                    v0[rt][1][i] = elu_f(acc0[rt][1][i] + p1 + Qr[col1] + base1);
                }
                {
                    unsigned e = e01 + rr;
                    bool hi = e >= eB1;
                    unsigned s = hi ? sB1 : sA1;
                    unsigned jj = e - (hi ? eB1 : baseE1);
                    unsigned rv = jj + (jj >= s ? 1u : 0u);
                    const float* Qr = Qb1 + rv * 128;
                    float p0 = hi ? pB1c0 : pA1c0, p1 = hi ? pB1c1 : pA1c1;
                    v1[rt][0][i] = elu_f(acc1[rt][0][i] + p0 + Qr[col0] + base0);
                    v1[rt][1][i] = elu_f(acc1[rt][1][i] + p1 + Qr[col1] + base1);
                }
            }
    }
    __syncthreads();
    vals_to_afrag(Afr0, v0, lane, w);
    vals_to_afrag(Afr1, v1, lane, w);
    __syncthreads();
#pragma unroll
    for (int rt = 0; rt < 4; ++rt)
#pragma unroll
        for (int c = 0; c < 2; ++c) {
            acc0[rt][c] = (f4v){0.f, 0.f, 0.f, 0.f};
            acc1[rt][c] = (f4v){0.f, 0.f, 0.f, 0.f};
        }
    gemm2_gw(Afr0, Afr1, w4p2, acc0, acc1, lane, w);
    // ep3: h4 = elu(acc + b2[col]) both tiles; merged column stats
#pragma unroll
    for (int ctl = 0; ctl < 2; ++ctl) {
        int col = (w * 2 + ctl) * 16 + cl;
        float bias = b2[col];
        float s1 = 0.f, s2 = 0.f;
#pragma unroll
        for (int rt = 0; rt < 4; ++rt)
#pragma unroll
            for (int i = 0; i < 4; ++i) {
                float va = elu_f(acc0[rt][ctl][i] + bias);
                float vb = elu_f(acc1[rt][ctl][i] + bias);
                v0[rt][ctl][i] = va;
                v1[rt][ctl][i] = vb;
                s1 += va + vb;
                s2 += va * va + vb * vb;
            }
        s1 += __shfl_xor(s1, 16);
        s2 += __shfl_xor(s2, 16);
        s1 += __shfl_xor(s1, 32);
        s2 += __shfl_xor(s2, 32);
        if (quad == 0) {
            atomicAdd(stc + col, s1);
            atomicAdd(stc + 128 + col, s2);
        }
    }
    __syncthreads();  // GEMM3 A-frag reads done; reuse Afr as fp16 tiles
    unsigned short* T0 = (unsigned short*)Afr0;
    unsigned short* T1 = (unsigned short*)Afr1;
#pragma unroll
    for (int ctl = 0; ctl < 2; ++ctl) {
        int col = (w * 2 + ctl) * 16 + cl;
#pragma unroll
        for (int rt = 0; rt < 4; ++rt)
#pragma unroll
            for (int i = 0; i < 4; ++i) {
                int rr = rt * 16 + quad * 4 + i;
                _Float16 ha = (_Float16)v0[rt][ctl][i];
                _Float16 hb = (_Float16)v1[rt][ctl][i];
                T0[rr * 128 + col] = *(unsigned short*)&ha;
                T1[rr * 128 + col] = *(unsigned short*)&hb;
            }
    }
    __syncthreads();
    {
        int rr = tid >> 2, cq = tid & 3;
#pragma unroll
        for (int i = 0; i < 4; ++i) {
            int off = rr * 128 + cq * 32 + i * 8;
            *(uint4*)(h4 + (size_t)row00 * 128 + off) = *(uint4*)&T0[off];
            *(uint4*)(h4 + (size_t)row01 * 128 + off) = *(uint4*)&T1[off];
        }
    }
}

// final: out[row,k] = sum_c (a4[c]*h4[row,c]+shift4[c]) * fcw[c,k] + fcb[k]
// h4 is fp16.
__global__ __launch_bounds__(256) void k_out(const unsigned short* __restrict__ h4,
                                             const float* __restrict__ coef4,
                                             const float* __restrict__ fcw,
                                             const float* __restrict__ fcb,
                                             float* __restrict__ out) {
    int tid = threadIdx.x;
    int lane = tid & 31, rsub = tid >> 5;
    int row = blockIdx.x * 8 + rsub;
    h4v hv = ((const h4v*)(h4 + (size_t)row * 128))[lane];
    float x0 = (float)hv[0], x1 = (float)hv[1], x2 = (float)hv[2], x3 = (float)hv[3];
    float4 a = ((const float4*)coef4)[lane];
    float4 c = ((const float4*)(coef4 + 128))[lane];
    x0 = a.x * x0 + c.x;
    x1 = a.y * x1 + c.y;
    x2 = a.z * x2 + c.z;
    x3 = a.w * x3 + c.w;
    const float4* W = (const float4*)(fcw + lane * 8);
    float4 w01 = W[0], w23 = W[1];
    float s0 = x0 * w01.x + x1 * w01.z + x2 * w23.x + x3 * w23.z;
    float s1 = x0 * w01.y + x1 * w01.w + x2 * w23.y + x3 * w23.w;
#pragma unroll
    for (int off = 16; off > 0; off >>= 1) {
        s0 += __shfl_down(s0, off, 32);
        s1 += __shfl_down(s1, off, 32);
    }
    if (lane == 0) {
        out[row * 2] = s0 + fcb[0];
        out[row * 2 + 1] = s1 + fcb[1];
    }
}

// ---------------------------------------------------------------------------

extern "C" void kernel_launch(void* const* d_in, const int* in_sizes, int n_in,
                              void* d_out, int out_size, void* d_ws, size_t ws_size,
                              hipStream_t stream) {
    const float* x = (const float*)d_in[0];
    const float* m1_w1 = (const float*)d_in[1];
    const float* m1_b1 = (const float*)d_in[2];
    const float* m1_w2 = (const float*)d_in[3];
    const float* m1_b2 = (const float*)d_in[4];
    const float* m1_g = (const float*)d_in[5];
    const float* m1_be = (const float*)d_in[6];
    const float* m2_w1 = (const float*)d_in[7];
    const float* m2_b1 = (const float*)d_in[8];
    const float* m2_w2 = (const float*)d_in[9];
    const float* m2_b2 = (const float*)d_in[10];
    const float* m2_g = (const float*)d_in[11];
    const float* m2_be = (const float*)d_in[12];
    const float* m3_w1 = (const float*)d_in[13];
    const float* m3_b1 = (const float*)d_in[14];
    const float* m3_w2 = (const float*)d_in[15];
    const float* m3_b2 = (const float*)d_in[16];
    const float* m3_g = (const float*)d_in[17];
    const float* m3_be = (const float*)d_in[18];
    const float* m4_w1 = (const float*)d_in[19];
    const float* m4_b1 = (const float*)d_in[20];
    const float* m4_w2 = (const float*)d_in[21];
    const float* m4_b2 = (const float*)d_in[22];
    const float* m4_g = (const float*)d_in[23];
    const float* m4_be = (const float*)d_in[24];
    const float* fc_w = (const float*)d_in[25];
    const float* fc_b = (const float*)d_in[26];
    float* out = (float*)d_out;

    float* W = (float*)d_ws;
    float* coef1 = W + OFF_COEF;
    float* coef2 = W + OFF_COEF + 256;
    float* coef3 = W + OFF_COEF + 512;
    float* coef4 = W + OFF_COEF + 768;
    float* cvec = W + OFF_CVEC;
    float* h1 = W + OFF_H1;        // aliased: aggraw; sums4 = h1[0:16384)
    float* aggraw = h1;
    float* sums4 = h1;
    float* P2 = W + OFF_P2;        // sums1 = P2[0:16384)
    float* sums1 = P2;
    float* Q2 = W + OFF_Q2;
    float* h3 = W + OFF_H3;
    float* P4 = W + OFF_P4;        // sums2 = P4[0:16384)
    float* sums2 = P4;
    float* Q4 = W + OFF_Q4;        // sums3 = Q4[0:16384)
    float* sums3 = Q4;
    _Float16* w2p2 = (_Float16*)(W + OFF_W2P);
    _Float16* w4p2 = (_Float16*)(W + OFF_W4P);
    _Float16* wcp = (_Float16*)(W + OFF_WCP);
    _Float16* h2f = (_Float16*)(W + OFF_H4B);             // h2 (fp16), then
    unsigned short* h4b = (unsigned short*)(W + OFF_H4B); // h4 (fp16) in place

    if (ws_size < WS_BYTES) return;  // safe-fail diagnostic (no OOB fault)

    k_prep<<<209, 256, 0, stream>>>(W, m2_w2, m4_w2);
    k_mlp1<<<128, 256, 0, stream>>>(x, m1_w1, m1_b1, m1_w2, m1_b2, h1, sums1);
    k_finalize<<<1, 128, 0, stream>>>(sums1, coef1, 1.f / 4096.f, m1_g, m1_be, nullptr);
    k_pq<<<256, 256, 0, stream>>>(h1, coef1, m2_w1, P2, Q2);
    k_mlp2agg<<<2048, 256, 0, stream>>>(P2, Q2, m2_b1, w2p2, m2_b2, aggraw, h2f, sums2);
    k_finalize<<<1, 128, 0, stream>>>(sums2, coef2, 1.f / 258048.f, m2_g, m2_be, nullptr);
    k_wcprep<<<128, 128, 0, stream>>>(m4_w1, coef2, wcp, cvec);
    k_mlp3<<<128, 256, 0, stream>>>(aggraw, coef2, m3_w1, m3_b1, m3_w2, m3_b2, h3, sums3);
    k_finalize<<<1, 128, 0, stream>>>(sums3, coef3, 1.f / 4096.f, m3_g, m3_be, sums4);
    k_pq<<<256, 256, 0, stream>>>(h3, coef3, m4_w1, P4, Q4);
    k_mlp4r2<<<2016, 256, 0, stream>>>(h2f, P4, Q4, wcp, cvec, m4_b1, w4p2, m4_b2,
                                       h4b, sums4);
    k_finalize<<<1, 128, 0, stream>>>(sums4, coef4, 1.f / 258048.f, m4_g, m4_be, nullptr);
    k_out<<<32256, 256, 0, stream>>>(h4b, coef4, fc_w, fc_b, out);
}

// Round 15
// 337.274 us; speedup vs baseline: 1.0463x; 1.0272x over previous
//
#include <hip/hip_runtime.h>

#define BN_EPS 1e-5f

using h8 = __attribute__((ext_vector_type(8))) _Float16;
using h4v = __attribute__((ext_vector_type(4))) _Float16;
using f4v = __attribute__((ext_vector_type(4))) float;

// workspace float offsets (proven layout). Slot/arena aliases:
//   sums1 (mlp1 slots, 128x256, plain stores)  = H3[0:32768)   (h3 dead then)
//   sums3 (mlp3 slots, 128x256, plain stores)  = P2[0:32768)   (P2 dead then)
//   sums2 (mlp2 arena, 64x256, atomics)        = P4[0:16384)
//   sums4 (mlp4 arena, 64x256, atomics)        = H1[0:16384)   (zeroed in pq4)
#define OFF_COEF 0        // coef2 only: a @ [0:128), shift @ [128:256)
#define OFF_CVEC 1024     // 128
#define OFF_H1 4096       // 4096x128 (aliased: aggraw; first 16384 = sums4)
#define OFF_P2 528384
#define OFF_Q2 1052672
#define OFF_H3 1576960
#define OFF_P4 2101248
#define OFF_Q4 2625536
#define OFF_W2P 3149824   // 16384 fp16 = 8192 floats each
#define OFF_W4P 3158016
#define OFF_WCP 3166208
#define OFF_H4B 3174400   // 258048x128 fp16: h2 then h4 in place
#define WS_BYTES 78757888ull

__device__ __forceinline__ float elu_f(float x) {
    return x > 0.f ? x : __expf(x) - 1.f;
}

// ---------------------------------------------------------------------------
// fp32 tile GEMM helpers (node-level kernels, 32-row tiles). Proven.
// ---------------------------------------------------------------------------

__device__ __forceinline__ void gemm32_globalW(const float* As, int lda,
                                               const float* __restrict__ Wg, int K,
                                               float acc[2][8], int tx, int ty) {
    const float4* Wg4 = (const float4*)Wg;
#pragma unroll 4
    for (int k = 0; k < K; ++k) {
        float a0 = As[ty * lda + k];
        float a1 = As[(ty + 16) * lda + k];
        float4 wa = Wg4[k * 32 + tx];
        float4 wb = Wg4[k * 32 + 16 + tx];
        const float wv[8] = {wa.x, wa.y, wa.z, wa.w, wb.x, wb.y, wb.z, wb.w};
#pragma unroll
        for (int u = 0; u < 8; ++u) {
            acc[0][u] = fmaf(a0, wv[u], acc[0][u]);
            acc[1][u] = fmaf(a1, wv[u], acc[1][u]);
        }
    }
}

__device__ __forceinline__ void bias_elu32(const float acc[2][8],
                                           const float* __restrict__ bias,
                                           float vals[2][8], int tx) {
    int ca = 4 * tx, cb = 64 + 4 * tx;
    float bv[8] = {bias[ca], bias[ca + 1], bias[ca + 2], bias[ca + 3],
                   bias[cb], bias[cb + 1], bias[cb + 2], bias[cb + 3]};
#pragma unroll
    for (int j = 0; j < 2; ++j)
#pragma unroll
        for (int u = 0; u < 8; ++u)
            vals[j][u] = elu_f(acc[j][u] + bv[u]);
}

__device__ __forceinline__ void store_tile32(float* __restrict__ out, int row0,
                                             const float vals[2][8], int tx, int ty) {
#pragma unroll
    for (int j = 0; j < 2; ++j) {
        int r = row0 + ty + 16 * j;
        *(float4*)(out + r * 128 + 4 * tx) =
            make_float4(vals[j][0], vals[j][1], vals[j][2], vals[j][3]);
        *(float4*)(out + r * 128 + 64 + 4 * tx) =
            make_float4(vals[j][4], vals[j][5], vals[j][6], vals[j][7]);
    }
}

// 32-row stats -> per-block slot (plain stores; no zero-init needed).
__device__ __forceinline__ void stats_tail32_store(const float vals[2][8], float* red,
                                                   float* __restrict__ slot, int tid,
                                                   int tx, int ty) {
    float ls[8], lq[8];
#pragma unroll
    for (int u = 0; u < 8; ++u) {
        ls[u] = vals[0][u] + vals[1][u];
        lq[u] = vals[0][u] * vals[0][u] + vals[1][u] * vals[1][u];
    }
    __syncthreads();
    int ca = 4 * tx, cb = 64 + 4 * tx;
#pragma unroll
    for (int u = 0; u < 4; ++u) {
        red[ty * 128 + ca + u] = ls[u];
        red[2048 + ty * 128 + ca + u] = lq[u];
        red[ty * 128 + cb + u] = ls[u + 4];
        red[2048 + ty * 128 + cb + u] = lq[u + 4];
    }
    __syncthreads();
    if (tid < 128) {
        float s = 0.f, q = 0.f;
#pragma unroll
        for (int t = 0; t < 16; ++t) {
            s += red[t * 128 + tid];
            q += red[2048 + t * 128 + tid];
        }
        slot[tid] = s;
        slot[128 + tid] = q;
    }
}

// ---------------------------------------------------------------------------
// MFMA helpers (proven).
// ---------------------------------------------------------------------------

__device__ __forceinline__ void gemm2_gw(const _Float16* A0, const _Float16* A1,
                                         const _Float16* __restrict__ wp,
                                         f4v acc0[4][2], f4v acc1[4][2], int lane, int w) {
#pragma unroll
    for (int kc = 0; kc < 4; ++kc) {
        h8 bf0 = *(const h8*)&wp[(((w * 2 + 0) * 4 + kc) * 64 + lane) * 8];
        h8 bf1 = *(const h8*)&wp[(((w * 2 + 1) * 4 + kc) * 64 + lane) * 8];
        h8 af0[4], af1[4];
#pragma unroll
        for (int rt = 0; rt < 4; ++rt) {
            af0[rt] = *(const h8*)&A0[((rt * 4 + kc) * 64 + lane) * 8];
            af1[rt] = *(const h8*)&A1[((rt * 4 + kc) * 64 + lane) * 8];
        }
#pragma unroll
        for (int rt = 0; rt < 4; ++rt) {
            acc0[rt][0] = __builtin_amdgcn_mfma_f32_16x16x32_f16(af0[rt], bf0, acc0[rt][0], 0, 0, 0);
            acc1[rt][0] = __builtin_amdgcn_mfma_f32_16x16x32_f16(af1[rt], bf0, acc1[rt][0], 0, 0, 0);
        }
#pragma unroll
        for (int rt = 0; rt < 4; ++rt) {
            acc0[rt][1] = __builtin_amdgcn_mfma_f32_16x16x32_f16(af0[rt], bf1, acc0[rt][1], 0, 0, 0);
            acc1[rt][1] = __builtin_amdgcn_mfma_f32_16x16x32_f16(af1[rt], bf1, acc1[rt][1], 0, 0, 0);
        }
    }
}

__device__ __forceinline__ void vals_to_afrag(_Float16* Afr, const float vals[4][2][4],
                                              int lane, int w) {
    int cl = lane & 15, quad = lane >> 4;
#pragma unroll
    for (int ctl = 0; ctl < 2; ++ctl) {
        int col = (w * 2 + ctl) * 16 + cl;
        int kc = col >> 5, o = (col >> 3) & 3, j = col & 7;
#pragma unroll
        for (int rt = 0; rt < 4; ++rt)
#pragma unroll
            for (int i = 0; i < 4; ++i) {
                int m = quad * 4 + i;
                Afr[((rt * 4 + kc) * 64 + o * 16 + m) * 8 + j] = (_Float16)vals[rt][ctl][i];
            }
    }
}

__device__ __forceinline__ void stage_pair(_Float16* Afr, const float4* __restrict__ Pr,
                                           const float4* __restrict__ Qr,
                                           const float4* __restrict__ B1, int lane, int kc) {
    int rt = lane >> 4, m = lane & 15;
#pragma unroll
    for (int o = 0; o < 4; ++o) {
        int c4 = kc * 8 + o * 2;
        float4 p0 = Pr[c4], q0 = Qr[c4], bb0 = B1[c4];
        float4 p1 = Pr[c4 + 1], q1 = Qr[c4 + 1], bb1 = B1[c4 + 1];
        h8 v;
        v[0] = (_Float16)elu_f(p0.x + q0.x + bb0.x);
        v[1] = (_Float16)elu_f(p0.y + q0.y + bb0.y);
        v[2] = (_Float16)elu_f(p0.z + q0.z + bb0.z);
        v[3] = (_Float16)elu_f(p0.w + q0.w + bb0.w);
        v[4] = (_Float16)elu_f(p1.x + q1.x + bb1.x);
        v[5] = (_Float16)elu_f(p1.y + q1.y + bb1.y);
        v[6] = (_Float16)elu_f(p1.z + q1.z + bb1.z);
        v[7] = (_Float16)elu_f(p1.w + q1.w + bb1.w);
        *(h8*)&Afr[((rt * 4 + kc) * 64 + o * 16 + m) * 8] = v;
    }
}

// ---------------------------------------------------------------------------
// Kernels
// ---------------------------------------------------------------------------

// mlp1 (32-row tiles, blocks 0..127, slot stats) + fused prep (blocks 128..208:
// zero sums2+cvec, pack w2/w4 layer-2 weights to fp16 frag layout).
__global__ __launch_bounds__(256) void k_mlp1p(const float* __restrict__ x,
                                               const float* __restrict__ w1,
                                               const float* __restrict__ b1,
                                               const float* __restrict__ w2,
                                               const float* __restrict__ b2,
                                               float* __restrict__ h1,
                                               float* __restrict__ slots,
                                               float* __restrict__ sums2,
                                               float* __restrict__ cvec,
                                               const float* __restrict__ w2src,
                                               _Float16* __restrict__ w2p,
                                               const float* __restrict__ w4src,
                                               _Float16* __restrict__ w4p) {
    __shared__ float Xs[32 * 44];
    __shared__ float As[32 * 132];
    int tid = threadIdx.x;
    int blk = blockIdx.x;
    if (blk >= 128) {
        if (blk < 193) {  // zeroing
            int i = (blk - 128) * 256 + tid;
            if (i < 16384) sums2[i] = 0.f;
            else if (i < 16512) cvec[i - 16384] = 0.f;
        } else {  // weight packing
            int second = blk >= 201;
            const float* src = second ? w4src : w2src;
            _Float16* wp = second ? w4p : w2p;
            int flat = (blk - (second ? 201 : 193)) * 256 + tid;  // 0..2047
            int g = flat >> 6, L = flat & 63;
            int ct = g >> 2, kc = g & 3;
            int nn = ct * 16 + (L & 15), k0 = kc * 32 + (L >> 4) * 8;
            h8 v;
#pragma unroll
            for (int j = 0; j < 8; ++j) v[j] = (_Float16)src[(k0 + j) * 128 + nn];
            *(h8*)&wp[flat * 8] = v;
        }
        return;
    }
    int tx = tid & 15, ty = tid >> 4;
    int r0 = blk * 32;
    for (int idx = tid; idx < 32 * 40; idx += 256) {
        int r = idx / 40, k = idx - r * 40;
        int rr = r0 + r, b = rr >> 6, n = rr & 63, t = k >> 2, d = k & 3;
        Xs[r * 44 + k] = x[((b * 10 + t) * 64 + n) * 4 + d];
    }
    __syncthreads();
    float acc[2][8] = {};
    gemm32_globalW(Xs, 44, w1, 40, acc, tx, ty);
    float vals[2][8];
    bias_elu32(acc, b1, vals, tx);
    int ca = 4 * tx, cb = 64 + 4 * tx;
#pragma unroll
    for (int j = 0; j < 2; ++j) {
        int r = ty + 16 * j;
#pragma unroll
        for (int u = 0; u < 4; ++u) {
            As[r * 132 + ca + u] = vals[j][u];
            As[r * 132 + cb + u] = vals[j][u + 4];
        }
    }
    __syncthreads();
    float acc2[2][8] = {};
    gemm32_globalW(As, 132, w2, 128, acc2, tx, ty);
    float vals2[2][8];
    bias_elu32(acc2, b2, vals2, tx);
    store_tile32(h1, r0, vals2, tx, ty);
    stats_tail32_store(vals2, As, slots + blk * 256, tid, tx, ty);
}

// P/Q precompute with fused BN-coef derivation from 128 plain-store slots.
// Optionally zeroes zero4[0:16384) distributed across the 256 blocks (pq4).
__global__ __launch_bounds__(256) void k_pqf(const float* __restrict__ h,
                                             const float* __restrict__ slots,
                                             const float* __restrict__ g,
                                             const float* __restrict__ beta,
                                             const float* __restrict__ w,
                                             float* __restrict__ P, float* __restrict__ Q,
                                             float* __restrict__ zero4) {
    __shared__ float Cf[256];
    __shared__ float As[32 * 132];
    int tid = threadIdx.x, tx = tid & 15, ty = tid >> 4;
    int half = blockIdx.x >> 7;
    int r0 = (blockIdx.x & 127) * 32;
    if (zero4 && tid < 64) zero4[blockIdx.x * 64 + tid] = 0.f;
    if (tid < 128) {
        int c = tid;
        float s = 0.f, q = 0.f;
#pragma unroll 8
        for (int t = 0; t < 128; ++t) {
            s += slots[t * 256 + c];
            q += slots[t * 256 + 128 + c];
        }
        float mean = s * (1.f / 4096.f);
        float var = q * (1.f / 4096.f) - mean * mean;
        float a = g[c] * rsqrtf(var + BN_EPS);
        Cf[c] = a;
        Cf[128 + c] = beta[c] - mean * a;
    }
    __syncthreads();
    const float* Wg = w + half * 128 * 128;
    float* out = half ? Q : P;
    const float4* h4p = (const float4*)h;
#pragma unroll
    for (int i = 0; i < 4; ++i) {
        int f4 = tid + i * 256;
        int r = f4 >> 5, c4 = f4 & 31;
        float4 hv = h4p[(r0 + r) * 32 + c4];
        int cb = c4 * 4;
        float4 v;
        v.x = Cf[cb] * hv.x + Cf[128 + cb];
        v.y = Cf[cb + 1] * hv.y + Cf[128 + cb + 1];
        v.z = Cf[cb + 2] * hv.z + Cf[128 + cb + 2];
        v.w = Cf[cb + 3] * hv.w + Cf[128 + cb + 3];
        *(float4*)(As + r * 132 + c4 * 4) = v;
    }
    __syncthreads();
    float acc[2][8] = {};
    gemm32_globalW(As, 132, Wg, 128, acc, tx, ty);
#pragma unroll
    for (int j = 0; j < 2; ++j) {
        int r = r0 + ty + 16 * j;
        *(float4*)(out + r * 128 + 4 * tx) = make_float4(acc[j][0], acc[j][1], acc[j][2], acc[j][3]);
        *(float4*)(out + r * 128 + 64 + 4 * tx) = make_float4(acc[j][4], acc[j][5], acc[j][6], acc[j][7]);
    }
}

// Recv-major fused mlp2 + edge2node + h2 materialization (round-12 proven).
__global__ __launch_bounds__(256, 3) void k_mlp2agg(const float* __restrict__ P2,
                                                    const float* __restrict__ Q2,
                                                    const float* __restrict__ b1,
                                                    const _Float16* __restrict__ w2p,
                                                    const float* __restrict__ b2,
                                                    float* __restrict__ aggraw,
                                                    _Float16* __restrict__ h2,
                                                    float* __restrict__ st) {
    __shared__ _Float16 Afr0[8192];
    __shared__ _Float16 Afr1[8192];
    int tid = threadIdx.x;
    int lane = tid & 63, w = tid >> 6, cl = lane & 15, quad = lane >> 4;
    int b = blockIdx.x >> 5, j2 = blockIdx.x & 31;
    int n0 = 2 * j2, n1 = n0 + 1;
    float* stc = st + (blockIdx.x & 63) * 256;
    {
        int r = lane;
        int s0 = (r < 63) ? (r + (r >= n0 ? 1 : 0)) : n0;  // row 63: dummy
        int s1i = (r < 63) ? (r + (r >= n1 ? 1 : 0)) : n1;
        const float4* B1 = (const float4*)b1;
        stage_pair(Afr0, (const float4*)(P2 + (b * 64 + s0) * 128),
                   (const float4*)(Q2 + (b * 64 + n0) * 128), B1, lane, w);
        stage_pair(Afr1, (const float4*)(P2 + (b * 64 + s1i) * 128),
                   (const float4*)(Q2 + (b * 64 + n1) * 128), B1, lane, w);
    }
    __syncthreads();
    f4v acc0[4][2], acc1[4][2];
#pragma unroll
    for (int rt = 0; rt < 4; ++rt)
#pragma unroll
        for (int c = 0; c < 2; ++c) {
            acc0[rt][c] = (f4v){0.f, 0.f, 0.f, 0.f};
            acc1[rt][c] = (f4v){0.f, 0.f, 0.f, 0.f};
        }
    gemm2_gw(Afr0, Afr1, w2p, acc0, acc1, lane, w);
    float v0[2][4][4], v1[2][4][4];
#pragma unroll
    for (int ctl = 0; ctl < 2; ++ctl) {
        int col = (w * 2 + ctl) * 16 + cl;
        float bias = b2[col];
        float a0 = 0.f, a1 = 0.f, sq = 0.f;
#pragma unroll
        for (int rt = 0; rt < 4; ++rt)
#pragma unroll
            for (int i = 0; i < 4; ++i) {
                int row = rt * 16 + quad * 4 + i;
                float va = elu_f(acc0[rt][ctl][i] + bias);
                float vb = elu_f(acc1[rt][ctl][i] + bias);
                if (row == 63) { va = 0.f; vb = 0.f; }
                v0[ctl][rt][i] = va;
                v1[ctl][rt][i] = vb;
                a0 += va;
                a1 += vb;
                sq += va * va + vb * vb;
            }
        a0 += __shfl_xor(a0, 16);
        a1 += __shfl_xor(a1, 16);
        sq += __shfl_xor(sq, 16);
        a0 += __shfl_xor(a0, 32);
        a1 += __shfl_xor(a1, 32);
        sq += __shfl_xor(sq, 32);
        if (quad == 0) {
            aggraw[(b * 64 + n0) * 128 + col] = a0;
            aggraw[(b * 64 + n1) * 128 + col] = a1;
            atomicAdd(stc + col, a0 + a1);
            atomicAdd(stc + 128 + col, sq);
        }
    }
    __syncthreads();
    unsigned short* T0 = (unsigned short*)Afr0;
    unsigned short* T1 = (unsigned short*)Afr1;
#pragma unroll
    for (int ctl = 0; ctl < 2; ++ctl) {
        int col = (w * 2 + ctl) * 16 + cl;
#pragma unroll
        for (int rt = 0; rt < 4; ++rt)
#pragma unroll
            for (int i = 0; i < 4; ++i) {
                int row = rt * 16 + quad * 4 + i;
                _Float16 ha = (_Float16)v0[ctl][rt][i];
                _Float16 hb = (_Float16)v1[ctl][rt][i];
                T0[row * 128 + col] = *(unsigned short*)&ha;
                T1[row * 128 + col] = *(unsigned short*)&hb;
            }
    }
    __syncthreads();
    {
        int rr = tid >> 2, cq = tid & 3;
        if (rr < 63) {
            int s0 = rr + (rr >= n0 ? 1 : 0);
            int e0 = s0 * 63 + (s0 > n0 ? n0 : n0 - 1);
            int s1i = rr + (rr >= n1 ? 1 : 0);
            int e1 = s1i * 63 + (s1i > n1 ? n1 : n1 - 1);
            unsigned short* d0 = (unsigned short*)h2 + ((size_t)b * 4032 + e0) * 128;
            unsigned short* d1 = (unsigned short*)h2 + ((size_t)b * 4032 + e1) * 128;
#pragma unroll
            for (int i = 0; i < 4; ++i) {
                int off = cq * 32 + i * 8;
                *(uint4*)(d0 + off) = *(uint4*)&T0[rr * 128 + off];
                *(uint4*)(d1 + off) = *(uint4*)&T1[rr * 128 + off];
            }
        }
    }
}

// fused BN2-finalize + wcprep: block k derives coef2[k] pair from the 64-slot
// atomic arena, writes it (for mlp3), then scales W4_1[256+k][:] into wcp and
// accumulates cvec.
__global__ __launch_bounds__(128) void k_wcfin(const float* __restrict__ sums2,
                                               const float* __restrict__ g2,
                                               const float* __restrict__ be2,
                                               const float* __restrict__ w41,
                                               _Float16* __restrict__ wcp,
                                               float* __restrict__ cvec,
                                               float* __restrict__ coef2) {
    __shared__ float red[128];
    __shared__ float pr[2];
    int k = blockIdx.x, c = threadIdx.x;  // 128 threads
    red[c] = (c < 64) ? sums2[c * 256 + k] : sums2[(c - 64) * 256 + 128 + k];
    __syncthreads();
    if (c == 0) {
        float s = 0.f, q = 0.f;
#pragma unroll 8
        for (int t = 0; t < 64; ++t) {
            s += red[t];
            q += red[64 + t];
        }
        float mean = s * (1.f / 258048.f);
        float var = q * (1.f / 258048.f) - mean * mean;
        float a = g2[k] * rsqrtf(var + BN_EPS);
        pr[0] = a;
        pr[1] = be2[k] - mean * a;
        coef2[k] = a;
        coef2[128 + k] = pr[1];
    }
    __syncthreads();
    float a2k = pr[0], sh2k = pr[1];
    float wv = w41[(256 + k) * 128 + c];
    int g = (c >> 4) * 4 + (k >> 5);
    int L = ((k >> 3) & 3) * 16 + (c & 15);
    int j = k & 7;
    wcp[(g * 64 + L) * 8 + j] = (_Float16)(a2k * wv);
    atomicAdd(&cvec[c], sh2k * wv);
}

// mlp3: 32-row tiles, 128 blocks, slot stats (plain stores into P2 arena).
__global__ __launch_bounds__(256) void k_mlp3(const float* __restrict__ raw,
                                              const float* __restrict__ coef2,
                                              const float* __restrict__ w1,
                                              const float* __restrict__ b1,
                                              const float* __restrict__ w2,
                                              const float* __restrict__ b2,
                                              float* __restrict__ h3,
                                              float* __restrict__ slots) {
    __shared__ float As[32 * 132];
    int tid = threadIdx.x, tx = tid & 15, ty = tid >> 4;
    int r0 = blockIdx.x * 32;
    const float4* in4 = (const float4*)raw;
    const float4* av = (const float4*)coef2;
    const float4* cv = (const float4*)(coef2 + 128);
    const float inv63 = 1.f / 63.f;
#pragma unroll
    for (int i = 0; i < 4; ++i) {
        int f4 = tid + i * 256;
        int r = f4 >> 5, c4 = f4 & 31;
        float4 hv = in4[(r0 + r) * 32 + c4];
        float4 a = av[c4], c = cv[c4];
        float4 v;
        v.x = a.x * hv.x * inv63 + c.x;
        v.y = a.y * hv.y * inv63 + c.y;
        v.z = a.z * hv.z * inv63 + c.z;
        v.w = a.w * hv.w * inv63 + c.w;
        *(float4*)(As + r * 132 + c4 * 4) = v;
    }
    __syncthreads();
    float acc[2][8] = {};
    gemm32_globalW(As, 132, w1, 128, acc, tx, ty);
    float vals[2][8];
    bias_elu32(acc, b1, vals, tx);
    __syncthreads();
    int ca = 4 * tx, cb = 64 + 4 * tx;
#pragma unroll
    for (int j = 0; j < 2; ++j) {
        int r = ty + 16 * j;
#pragma unroll
        for (int u = 0; u < 4; ++u) {
            As[r * 132 + ca + u] = vals[j][u];
            As[r * 132 + cb + u] = vals[j][u + 4];
        }
    }
    __syncthreads();
    float acc2[2][8] = {};
    gemm32_globalW(As, 132, w2, 128, acc2, tx, ty);
    float vals2[2][8];
    bias_elu32(acc2, b2, vals2, tx);
    store_tile32(h3, r0, vals2, tx, ty);
    stats_tail32_store(vals2, As, slots + blockIdx.x * 256, tid, tx, ty);
}

// mlp4 edge kernel (round-12 proven, unchanged).
__global__ __launch_bounds__(256, 3) void k_mlp4r2(const _Float16* __restrict__ h2,
                                                   const float* __restrict__ P4,
                                                   const float* __restrict__ Q4,
                                                   const _Float16* __restrict__ wcp,
                                                   const float* __restrict__ cvec,
                                                   const float* __restrict__ b1,
                                                   const _Float16* __restrict__ w4p2,
                                                   const float* __restrict__ b2,
                                                   unsigned short* __restrict__ h4,
                                                   float* __restrict__ st) {
    __shared__ _Float16 Afr0[8192];
    __shared__ _Float16 Afr1[8192];
    int tid = threadIdx.x;
    int lane = tid & 63, w = tid >> 6, cl = lane & 15, quad = lane >> 4;
    unsigned t0 = 2u * blockIdx.x, t1 = t0 + 1u;
    unsigned b0 = t0 / 63, b1i = t1 / 63;
    unsigned e00 = (t0 - b0 * 63) * 64, e01 = (t1 - b1i * 63) * 64;
    int row00 = t0 * 64, row01 = t1 * 64;
    float* stc = st + (blockIdx.x & 63) * 256;
#pragma unroll
    for (int i = 0; i < 4; ++i) {
        int u = tid + i * 256;
        int r = u >> 4, cu = u & 15;
        int dst = (((r >> 4) * 4 + (cu >> 2)) * 64 + (cu & 3) * 16 + (r & 15)) * 8;
        *(h8*)&Afr0[dst] = *(const h8*)&h2[(size_t)(row00 + r) * 128 + cu * 8];
        *(h8*)&Afr1[dst] = *(const h8*)&h2[(size_t)(row01 + r) * 128 + cu * 8];
    }
    __syncthreads();
    f4v acc0[4][2], acc1[4][2];
#pragma unroll
    for (int rt = 0; rt < 4; ++rt)
#pragma unroll
        for (int c = 0; c < 2; ++c) {
            acc0[rt][c] = (f4v){0.f, 0.f, 0.f, 0.f};
            acc1[rt][c] = (f4v){0.f, 0.f, 0.f, 0.f};
        }
    gemm2_gw(Afr0, Afr1, wcp, acc0, acc1, lane, w);
    float v0[4][2][4], v1[4][2][4];
    {
        int col0 = w * 32 + cl, col1 = col0 + 16;
        float base0 = b1[col0] + cvec[col0];
        float base1 = b1[col1] + cvec[col1];
        unsigned sA0 = e00 / 63, sA1 = e01 / 63;
        unsigned baseE0 = sA0 * 63, baseE1 = sA1 * 63;
        unsigned eB0 = baseE0 + 63, eB1 = baseE1 + 63;
        unsigned sB0 = sA0 < 63u ? sA0 + 1u : sA0;
        unsigned sB1 = sA1 < 63u ? sA1 + 1u : sA1;
        const float* PA0 = P4 + (b0 * 64 + sA0) * 128;
        const float* PB0 = P4 + (b0 * 64 + sB0) * 128;
        const float* PA1 = P4 + (b1i * 64 + sA1) * 128;
        const float* PB1 = P4 + (b1i * 64 + sB1) * 128;
        float pA0c0 = PA0[col0], pA0c1 = PA0[col1];
        float pB0c0 = PB0[col0], pB0c1 = PB0[col1];
        float pA1c0 = PA1[col0], pA1c1 = PA1[col1];
        float pB1c0 = PB1[col0], pB1c1 = PB1[col1];
        const float* Qb0 = Q4 + (size_t)b0 * 8192;
        const float* Qb1 = Q4 + (size_t)b1i * 8192;
#pragma unroll
        for (int rt = 0; rt < 4; ++rt)
#pragma unroll
            for (int i = 0; i < 4; ++i) {
                int rr = rt * 16 + quad * 4 + i;
                {
                    unsigned e = e00 + rr;
                    bool hi = e >= eB0;
                    unsigned s = hi ? sB0 : sA0;
                    unsigned jj = e - (hi ? eB0 : baseE0);
                    unsigned rv = jj + (jj >= s ? 1u : 0u);
                    const float* Qr = Qb0 + rv * 128;
                    float p0 = hi ? pB0c0 : pA0c0, p1 = hi ? pB0c1 : pA0c1;
                    v0[rt][0][i] = elu_f(acc0[rt][0][i] + p0 + Qr[col0] + base0);
                    v0[rt][1][i] = elu_f(acc0[rt][1][i] + p1 + Qr[col1] + base1);
                }
                {
                    unsigned e = e01 + rr;
                    bool hi = e >= eB1;
                    unsigned s = hi ? sB1 : sA1;
                    unsigned jj = e - (hi ? eB1 : baseE1);
                    unsigned rv = jj + (jj >= s ? 1u : 0u);
                    const float* Qr = Qb1 + rv * 128;
                    float p0 = hi ? pB1c0 : pA1c0, p1 = hi ? pB1c1 : pA1c1;
                    v1[rt][0][i] = elu_f(acc1[rt][0][i] + p0 + Qr[col0] + base0);
                    v1[rt][1][i] = elu_f(acc1[rt][1][i] + p1 + Qr[col1] + base1);
                }
            }
    }
    __syncthreads();
    vals_to_afrag(Afr0, v0, lane, w);
    vals_to_afrag(Afr1, v1, lane, w);
    __syncthreads();
#pragma unroll
    for (int rt = 0; rt < 4; ++rt)
#pragma unroll
        for (int c = 0; c < 2; ++c) {
            acc0[rt][c] = (f4v){0.f, 0.f, 0.f, 0.f};
            acc1[rt][c] = (f4v){0.f, 0.f, 0.f, 0.f};
        }
    gemm2_gw(Afr0, Afr1, w4p2, acc0, acc1, lane, w);
#pragma unroll
    for (int ctl = 0; ctl < 2; ++ctl) {
        int col = (w * 2 + ctl) * 16 + cl;
        float bias = b2[col];
        float s1 = 0.f, s2 = 0.f;
#pragma unroll
        for (int rt = 0; rt < 4; ++rt)
#pragma unroll
            for (int i = 0; i < 4; ++i) {
                float va = elu_f(acc0[rt][ctl][i] + bias);
                float vb = elu_f(acc1[rt][ctl][i] + bias);
                v0[rt][ctl][i] = va;
                v1[rt][ctl][i] = vb;
                s1 += va + vb;
                s2 += va * va + vb * vb;
            }
        s1 += __shfl_xor(s1, 16);
        s2 += __shfl_xor(s2, 16);
        s1 += __shfl_xor(s1, 32);
        s2 += __shfl_xor(s2, 32);
        if (quad == 0) {
            atomicAdd(stc + col, s1);
            atomicAdd(stc + 128 + col, s2);
        }
    }
    __syncthreads();
    unsigned short* T0 = (unsigned short*)Afr0;
    unsigned short* T1 = (unsigned short*)Afr1;
#pragma unroll
    for (int ctl = 0; ctl < 2; ++ctl) {
        int col = (w * 2 + ctl) * 16 + cl;
#pragma unroll
        for (int rt = 0; rt < 4; ++rt)
#pragma unroll
            for (int i = 0; i < 4; ++i) {
                int rr = rt * 16 + quad * 4 + i;
                _Float16 ha = (_Float16)v0[rt][ctl][i];
                _Float16 hb = (_Float16)v1[rt][ctl][i];
                T0[rr * 128 + col] = *(unsigned short*)&ha;
                T1[rr * 128 + col] = *(unsigned short*)&hb;
            }
    }
    __syncthreads();
    {
        int rr = tid >> 2, cq = tid & 3;
#pragma unroll
        for (int i = 0; i < 4; ++i) {
            int off = rr * 128 + cq * 32 + i * 8;
            *(uint4*)(h4 + (size_t)row00 * 128 + off) = *(uint4*)&T0[off];
            *(uint4*)(h4 + (size_t)row01 * 128 + off) = *(uint4*)&T1[off];
        }
    }
}

// fused BN4-finalize + fc output: 1008 blocks x 256 rows; coef4 derived per
// block in LDS from the 64-slot atomic arena.
__global__ __launch_bounds__(256) void k_outf(const unsigned short* __restrict__ h4,
                                              const float* __restrict__ sums4,
                                              const float* __restrict__ g4,
                                              const float* __restrict__ be4,
                                              const float* __restrict__ fcw,
                                              const float* __restrict__ fcb,
                                              float* __restrict__ out) {
    __shared__ float Cf[256];
    int tid = threadIdx.x;
    if (tid < 128) {
        int c = tid;
        float s = 0.f, q = 0.f;
#pragma unroll 8
        for (int t = 0; t < 64; ++t) {
            s += sums4[t * 256 + c];
            q += sums4[t * 256 + 128 + c];
        }
        float mean = s * (1.f / 258048.f);
        float var = q * (1.f / 258048.f) - mean * mean;
        float a = g4[c] * rsqrtf(var + BN_EPS);
        Cf[c] = a;
        Cf[128 + c] = be4[c] - mean * a;
    }
    __syncthreads();
    int lane = tid & 31, rsub = tid >> 5;
    const float4* Wp = (const float4*)(fcw + lane * 8);
    float4 w01 = Wp[0], w23 = Wp[1];
    float fb0 = fcb[0], fb1 = fcb[1];
    float a0 = Cf[lane * 4], a1 = Cf[lane * 4 + 1], a2 = Cf[lane * 4 + 2], a3 = Cf[lane * 4 + 3];
    float c0 = Cf[128 + lane * 4], c1 = Cf[128 + lane * 4 + 1];
    float c2 = Cf[128 + lane * 4 + 2], c3 = Cf[128 + lane * 4 + 3];
    size_t base = (size_t)blockIdx.x * 256;
#pragma unroll 4
    for (int it = 0; it < 32; ++it) {
        size_t row = base + it * 8 + rsub;
        h4v hv = ((const h4v*)(h4 + row * 128))[lane];
        float x0 = a0 * (float)hv[0] + c0;
        float x1 = a1 * (float)hv[1] + c1;
        float x2 = a2 * (float)hv[2] + c2;
        float x3 = a3 * (float)hv[3] + c3;
        float s0 = x0 * w01.x + x1 * w01.z + x2 * w23.x + x3 * w23.z;
        float s1 = x0 * w01.y + x1 * w01.w + x2 * w23.y + x3 * w23.w;
#pragma unroll
        for (int off = 16; off > 0; off >>= 1) {
            s0 += __shfl_down(s0, off, 32);
            s1 += __shfl_down(s1, off, 32);
        }
        if (lane == 0) {
            out[row * 2] = s0 + fb0;
            out[row * 2 + 1] = s1 + fb1;
        }
    }
}

// ---------------------------------------------------------------------------

extern "C" void kernel_launch(void* const* d_in, const int* in_sizes, int n_in,
                              void* d_out, int out_size, void* d_ws, size_t ws_size,
                              hipStream_t stream) {
    const float* x = (const float*)d_in[0];
    const float* m1_w1 = (const float*)d_in[1];
    const float* m1_b1 = (const float*)d_in[2];
    const float* m1_w2 = (const float*)d_in[3];
    const float* m1_b2 = (const float*)d_in[4];
    const float* m1_g = (const float*)d_in[5];
    const float* m1_be = (const float*)d_in[6];
    const float* m2_w1 = (const float*)d_in[7];
    const float* m2_b1 = (const float*)d_in[8];
    const float* m2_w2 = (const float*)d_in[9];
    const float* m2_b2 = (const float*)d_in[10];
    const float* m2_g = (const float*)d_in[11];
    const float* m2_be = (const float*)d_in[12];
    const float* m3_w1 = (const float*)d_in[13];
    const float* m3_b1 = (const float*)d_in[14];
    const float* m3_w2 = (const float*)d_in[15];
    const float* m3_b2 = (const float*)d_in[16];
    const float* m3_g = (const float*)d_in[17];
    const float* m3_be = (const float*)d_in[18];
    const float* m4_w1 = (const float*)d_in[19];
    const float* m4_b1 = (const float*)d_in[20];
    const float* m4_w2 = (const float*)d_in[21];
    const float* m4_b2 = (const float*)d_in[22];
    const float* m4_g = (const float*)d_in[23];
    const float* m4_be = (const float*)d_in[24];
    const float* fc_w = (const float*)d_in[25];
    const float* fc_b = (const float*)d_in[26];
    float* out = (float*)d_out;

    float* W = (float*)d_ws;
    float* coef2 = W + OFF_COEF;
    float* cvec = W + OFF_CVEC;
    float* h1 = W + OFF_H1;            // aliased: aggraw; sums4 = h1[0:16384)
    float* aggraw = h1;
    float* sums4 = h1;
    float* P2 = W + OFF_P2;            // sums3 slots = P2[0:32768) (P2 dead then)
    float* sums3 = P2;
    float* Q2 = W + OFF_Q2;
    float* h3 = W + OFF_H3;            // sums1 slots = h3[0:32768) (h3 written later)
    float* sums1 = h3;
    float* P4 = W + OFF_P4;            // sums2 arena = P4[0:16384)
    float* sums2 = P4;
    float* Q4 = W + OFF_Q4;
    _Float16* w2p2 = (_Float16*)(W + OFF_W2P);
    _Float16* w4p2 = (_Float16*)(W + OFF_W4P);
    _Float16* wcp = (_Float16*)(W + OFF_WCP);
    _Float16* h2f = (_Float16*)(W + OFF_H4B);             // h2 (fp16), then
    unsigned short* h4b = (unsigned short*)(W + OFF_H4B); // h4 (fp16) in place

    if (ws_size < WS_BYTES) return;  // safe-fail diagnostic (no OOB fault)

    k_mlp1p<<<209, 256, 0, stream>>>(x, m1_w1, m1_b1, m1_w2, m1_b2, h1, sums1,
                                     sums2, cvec, m2_w2, w2p2, m4_w2, w4p2);
    k_pqf<<<256, 256, 0, stream>>>(h1, sums1, m1_g, m1_be, m2_w1, P2, Q2, nullptr);
    k_mlp2agg<<<2048, 256, 0, stream>>>(P2, Q2, m2_b1, w2p2, m2_b2, aggraw, h2f, sums2);
    k_wcfin<<<128, 128, 0, stream>>>(sums2, m2_g, m2_be, m4_w1, wcp, cvec, coef2);
    k_mlp3<<<128, 256, 0, stream>>>(aggraw, coef2, m3_w1, m3_b1, m3_w2, m3_b2, h3, sums3);
    k_pqf<<<256, 256, 0, stream>>>(h3, sums3, m3_g, m3_be, m4_w1, P4, Q4, sums4);
    k_mlp4r2<<<2016, 256, 0, stream>>>(h2f, P4, Q4, wcp, cvec, m4_b1, w4p2, m4_b2,
                                       h4b, sums4);
    k_outf<<<1008, 256, 0, stream>>>(h4b, sums4, m4_g, m4_be, fc_w, fc_b, out);
}